// Round 5
// baseline (335.315 us; speedup 1.0000x reference)
//
#include <hip/hip_runtime.h>

#define N_NODES 50000
#define N_EDGES 800000
#define DIM 128
#define NUM_REL 200
#define NREL2 (2 * NUM_REL)
#define SCAN_BLK 512
#define SCAN_NBLK ((N_NODES + SCAN_BLK - 1) / SCAN_BLK)  // 98

// ---------------------------------------------------------------------------
// Kernel A: merged relation table R[400][128] (W_O rel-half for t<200, W_I
// rel-half else, + matching bias) and rel_new output (rel_emb @ W_R^T + b_R).
// ---------------------------------------------------------------------------
__global__ void rel_tables_kernel(const float* __restrict__ rel_emb,
                                  const float* __restrict__ W_O_w,
                                  const float* __restrict__ W_O_b,
                                  const float* __restrict__ W_I_w,
                                  const float* __restrict__ W_I_b,
                                  const float* __restrict__ W_R_w,
                                  const float* __restrict__ W_R_b,
                                  float* __restrict__ R,
                                  float* __restrict__ rel_new) {
    __shared__ float row[DIM];
    const int t = blockIdx.x;   // 0..399
    const int j = threadIdx.x;  // 0..127
    row[j] = rel_emb[t * DIM + j];
    __syncthreads();

    const bool fwd = (t < NUM_REL);
    const float* __restrict__ wSel = (fwd ? W_O_w : W_I_w) + j * (2 * DIM);
    const float* __restrict__ wR = W_R_w + j * DIM;

    float aSel = 0.f, aR = 0.f;
#pragma unroll 8
    for (int k = 0; k < DIM; ++k) {
        const float e = row[k];
        aSel += e * wSel[k];
        aR += e * wR[k];
    }
    R[t * DIM + j] = aSel + (fwd ? W_O_b[j] : W_I_b[j]);
    rel_new[t * DIM + j] = aR + W_R_b[j];
}

// ---------------------------------------------------------------------------
// Kernel B (v4): register-tiled fp32 GEMM. Block = 64 nodes x 128 cols;
// gridDim.y picks the matrix (0: W_O ent-half -> EE, 1: W_I ent-half ->
// EE+N*DIM, 2: W_S -> ent_S with bias). Thread (c,r) = col-quad x node-oct
// computes 8 nodes x 4 cols = 8 float4 accumulators.
// Per k4: 8 ds_read_b128 (2 distinct addrs/wave = free aliasing) +
// 4 weight f4 (L1/L2) + 128 FMA -> FMA-bound, unlike v3's 16 LDS : 64 FMA.
// ---------------------------------------------------------------------------
#define REP8(F) F(0) F(1) F(2) F(3) F(4) F(5) F(6) F(7)

__global__ void __launch_bounds__(256)
node_gemm_kernel(const float* __restrict__ ent_emb,
                 const float* __restrict__ W_O_w,
                 const float* __restrict__ W_I_w,
                 const float* __restrict__ W_S_w,
                 const float* __restrict__ W_S_b,
                 float* __restrict__ EE,
                 float* __restrict__ ent_S) {
    __shared__ float4 tile[64 * 32];  // 32 KB: 64 node rows x 32 f4
    const int t = threadIdx.x;
    const int n0 = blockIdx.x * 64;
    const int y = blockIdx.y;

    // Stage 64 node rows (2048 f4), coalesced, zero-padded at the tail.
#pragma unroll
    for (int i = 0; i < 8; ++i) {
        const int fi = i * 256 + t;
        const int n = n0 + (fi >> 5);
        float4 v = make_float4(0.f, 0.f, 0.f, 0.f);
        if (n < N_NODES) v = *(const float4*)(ent_emb + (size_t)n * DIM + (fi & 31) * 4);
        tile[fi] = v;
    }
    __syncthreads();

    const int c = t & 31;  // col quad -> cols j..j+3
    const int r = t >> 5;  // node oct -> nodes n0+r*8..+7
    const int j = c * 4;

    const float* wbase;
    int ldw;
    float* obase;
    float4 bias = make_float4(0.f, 0.f, 0.f, 0.f);
    if (y == 0) {
        wbase = W_O_w + DIM;  // ent-half
        ldw = 2 * DIM;
        obase = EE;
    } else if (y == 1) {
        wbase = W_I_w + DIM;
        ldw = 2 * DIM;
        obase = EE + (size_t)N_NODES * DIM;
    } else {
        wbase = W_S_w;
        ldw = DIM;
        obase = ent_S;
        bias = *(const float4*)(W_S_b + j);
    }

    const float* __restrict__ w0 = wbase + (size_t)(j + 0) * ldw;
    const float* __restrict__ w1 = wbase + (size_t)(j + 1) * ldw;
    const float* __restrict__ w2 = wbase + (size_t)(j + 2) * ldw;
    const float* __restrict__ w3 = wbase + (size_t)(j + 3) * ldw;

#define DECL(m) float4 A##m = make_float4(0.f, 0.f, 0.f, 0.f);
    REP8(DECL)
#undef DECL

    const float4* __restrict__ ebase = tile + r * 8 * 32;

#pragma unroll 4
    for (int k4 = 0; k4 < 32; ++k4) {
        const float4 wa = *(const float4*)(w0 + k4 * 4);
        const float4 wb = *(const float4*)(w1 + k4 * 4);
        const float4 wc = *(const float4*)(w2 + k4 * 4);
        const float4 wd = *(const float4*)(w3 + k4 * 4);
#define STEP(m)                                                      \
        {                                                            \
            const float4 e = ebase[(m) * 32 + k4];                   \
            A##m.x += e.x * wa.x + e.y * wa.y + e.z * wa.z + e.w * wa.w; \
            A##m.y += e.x * wb.x + e.y * wb.y + e.z * wb.z + e.w * wb.w; \
            A##m.z += e.x * wc.x + e.y * wc.y + e.z * wc.z + e.w * wc.w; \
            A##m.w += e.x * wd.x + e.y * wd.y + e.z * wd.z + e.w * wd.w; \
        }
        REP8(STEP)
#undef STEP
    }

#define STORE(m)                                                     \
    {                                                                \
        const int n = n0 + r * 8 + (m);                              \
        if (n < N_NODES) {                                           \
            float4 o;                                                \
            o.x = A##m.x + bias.x;                                   \
            o.y = A##m.y + bias.y;                                   \
            o.z = A##m.z + bias.z;                                   \
            o.w = A##m.w + bias.w;                                   \
            *(float4*)(obase + (size_t)n * DIM + j) = o;             \
        }                                                            \
    }
    REP8(STORE)
#undef STORE
}

// ---------------------------------------------------------------------------
// CSR construction: histogram -> 3-phase exclusive scan -> fill.
// ---------------------------------------------------------------------------
__global__ void __launch_bounds__(256)
hist_kernel(const int* __restrict__ dst, int* __restrict__ counts) {
    const int e = blockIdx.x * 256 + threadIdx.x;
    if (e < N_EDGES) atomicAdd(&counts[dst[e]], 1);
}

__global__ void __launch_bounds__(SCAN_BLK)
scan1_kernel(const int* __restrict__ counts, int* __restrict__ offs,
             int* __restrict__ bsum) {
    __shared__ int tmp[SCAN_BLK];
    const int i = blockIdx.x * SCAN_BLK + threadIdx.x;
    const int v = (i < N_NODES) ? counts[i] : 0;
    tmp[threadIdx.x] = v;
    __syncthreads();
    for (int off = 1; off < SCAN_BLK; off <<= 1) {
        const int t = (threadIdx.x >= off) ? tmp[threadIdx.x - off] : 0;
        __syncthreads();
        tmp[threadIdx.x] += t;
        __syncthreads();
    }
    if (i < N_NODES) offs[i] = tmp[threadIdx.x] - v;  // exclusive
    if (threadIdx.x == SCAN_BLK - 1) bsum[blockIdx.x] = tmp[SCAN_BLK - 1];
}

// 128-thread LDS scan of the 98 block sums (replaces the serial 1-thread
// version whose 98 dependent global loads cost ~10 us).
__global__ void __launch_bounds__(128)
scan2_kernel(int* __restrict__ bsum) {
    __shared__ int tmp[128];
    const int i = threadIdx.x;
    const int v = (i < SCAN_NBLK) ? bsum[i] : 0;
    tmp[i] = v;
    __syncthreads();
    for (int off = 1; off < 128; off <<= 1) {
        const int tv = (i >= off) ? tmp[i - off] : 0;
        __syncthreads();
        tmp[i] += tv;
        __syncthreads();
    }
    if (i < SCAN_NBLK) bsum[i] = tmp[i] - v;  // exclusive
}

__global__ void __launch_bounds__(SCAN_BLK)
scan3_kernel(int* __restrict__ offs, const int* __restrict__ bsum) {
    const int i = blockIdx.x * SCAN_BLK + threadIdx.x;
    if (i < N_NODES) offs[i] += bsum[blockIdx.x];
}

// Fill: sorted-by-dst packed edge payload: row(17b) | etype<<17 (9b).
__global__ void __launch_bounds__(256)
fill_kernel(const int* __restrict__ src, const int* __restrict__ dst,
            const int* __restrict__ et, const int* __restrict__ offs,
            int* __restrict__ cursor, int* __restrict__ sp) {
    const int e = blockIdx.x * 256 + threadIdx.x;
    if (e >= N_EDGES) return;
    const int d = dst[e];
    const int t = et[e];
    const int row = src[e] + ((t < NUM_REL) ? 0 : N_NODES);
    const int pos = atomicAdd(&cursor[d], 1);
    sp[offs[d] + pos] = row | (t << 17);
}

// ---------------------------------------------------------------------------
// Gather-reduce: one wave per node. Lane l owns output floats [2l, 2l+1].
// Fuses finalize: out = ent_S + acc / max(deg,1).  (Unchanged — its counters
// surface next round once node_gemm shrinks.)
// ---------------------------------------------------------------------------
__global__ void __launch_bounds__(256)
gather_kernel(const int* __restrict__ offs, const int* __restrict__ counts,
              const int* __restrict__ sp, const float* __restrict__ EE,
              const float* __restrict__ R, const float* __restrict__ ent_S,
              float* __restrict__ out_ent) {
    const int node = blockIdx.x * 4 + (threadIdx.x >> 6);
    if (node >= N_NODES) return;
    const int l = threadIdx.x & 63;

    const int beg = offs[node];
    const int cnt = counts[node];

    float ax = 0.f, ay = 0.f;
    for (int base = 0; base < cnt; base += 64) {
        const int kk = min(64, cnt - base);
        const int myp = (base + l < cnt) ? sp[beg + base + l] : 0;
#pragma unroll 4
        for (int i = 0; i < kk; ++i) {
            const int p = __shfl(myp, i);
            const int row = p & 0x1FFFF;
            const int t = p >> 17;
            const float2 e = *(const float2*)(EE + (size_t)row * DIM + 2 * l);
            const float2 r = *(const float2*)(R + (size_t)t * DIM + 2 * l);
            ax += e.x + r.x;
            ay += e.y + r.y;
        }
    }

    const float inv = 1.0f / fmaxf((float)cnt, 1.0f);
    const float2 s = *(const float2*)(ent_S + (size_t)node * DIM + 2 * l);
    float2 o;
    o.x = s.x + ax * inv;
    o.y = s.y + ay * inv;
    *(float2*)(out_ent + (size_t)node * DIM + 2 * l) = o;
}

extern "C" void kernel_launch(void* const* d_in, const int* in_sizes, int n_in,
                              void* d_out, int out_size, void* d_ws, size_t ws_size,
                              hipStream_t stream) {
    const int* src = (const int*)d_in[0];
    const int* dst = (const int*)d_in[1];
    const int* et = (const int*)d_in[2];
    const float* ent_emb = (const float*)d_in[3];
    const float* rel_emb = (const float*)d_in[4];
    const float* W_O_w = (const float*)d_in[5];
    const float* W_O_b = (const float*)d_in[6];
    const float* W_I_w = (const float*)d_in[7];
    const float* W_I_b = (const float*)d_in[8];
    const float* W_S_w = (const float*)d_in[9];
    const float* W_S_b = (const float*)d_in[10];
    const float* W_R_w = (const float*)d_in[11];
    const float* W_R_b = (const float*)d_in[12];

    float* out_ent = (float*)d_out;                    // [50000*128]
    float* out_rel = out_ent + (size_t)N_NODES * DIM;  // [400*128]

    // Workspace layout: R | EE | ent_S | counts,cursor | bsum | offs | sp
    float* wsf = (float*)d_ws;
    float* R = wsf;
    wsf += (size_t)NREL2 * DIM;          // 51,200 f
    float* EE = wsf;
    wsf += (size_t)2 * N_NODES * DIM;    // 12.8M f
    float* ent_S = wsf;
    wsf += (size_t)N_NODES * DIM;        // 6.4M f
    int* counts = (int*)wsf;
    int* cursor = counts + N_NODES;
    int* bsum = cursor + N_NODES;
    int* offs = bsum + 128;
    int* sp = offs + N_NODES;
    // total ~80.8 MB

    hipMemsetAsync(counts, 0, 2 * N_NODES * sizeof(int), stream);

    rel_tables_kernel<<<NREL2, DIM, 0, stream>>>(rel_emb, W_O_w, W_O_b, W_I_w, W_I_b,
                                                 W_R_w, W_R_b, R, out_rel);

    node_gemm_kernel<<<dim3((N_NODES + 63) / 64, 3), 256, 0, stream>>>(
        ent_emb, W_O_w, W_I_w, W_S_w, W_S_b, EE, ent_S);

    hist_kernel<<<(N_EDGES + 255) / 256, 256, 0, stream>>>(dst, counts);
    scan1_kernel<<<SCAN_NBLK, SCAN_BLK, 0, stream>>>(counts, offs, bsum);
    scan2_kernel<<<1, 128, 0, stream>>>(bsum);
    scan3_kernel<<<SCAN_NBLK, SCAN_BLK, 0, stream>>>(offs, bsum);
    fill_kernel<<<(N_EDGES + 255) / 256, 256, 0, stream>>>(src, dst, et, offs, cursor, sp);

    gather_kernel<<<(N_NODES + 3) / 4, 256, 0, stream>>>(offs, counts, sp, EE, R, ent_S,
                                                         out_ent);
}

// Round 6
// 271.582 us; speedup vs baseline: 1.2347x; 1.2347x over previous
//
#include <hip/hip_runtime.h>
#include <hip/hip_bf16.h>

#define N_NODES 50000
#define N_EDGES 800000
#define DIM 128
#define NUM_REL 200
#define NREL2 (2 * NUM_REL)
#define SCAN_BLK 512
#define SCAN_NBLK ((N_NODES + SCAN_BLK - 1) / SCAN_BLK)  // 98
#define NROWG (N_NODES / 16)  // 3125 row groups of 16 nodes

typedef __bf16 bf16x8 __attribute__((ext_vector_type(8)));
typedef float f32x4 __attribute__((ext_vector_type(4)));

// ---------------------------------------------------------------------------
// Kernel A: merged relation table R[400][128] (W_O rel-half for t<200, W_I
// rel-half else, + matching bias) and rel_new output (rel_emb @ W_R^T + b_R).
// ---------------------------------------------------------------------------
__global__ void rel_tables_kernel(const float* __restrict__ rel_emb,
                                  const float* __restrict__ W_O_w,
                                  const float* __restrict__ W_O_b,
                                  const float* __restrict__ W_I_w,
                                  const float* __restrict__ W_I_b,
                                  const float* __restrict__ W_R_w,
                                  const float* __restrict__ W_R_b,
                                  float* __restrict__ R,
                                  float* __restrict__ rel_new) {
    __shared__ float row[DIM];
    const int t = blockIdx.x;   // 0..399
    const int j = threadIdx.x;  // 0..127
    row[j] = rel_emb[t * DIM + j];
    __syncthreads();

    const bool fwd = (t < NUM_REL);
    const float* __restrict__ wSel = (fwd ? W_O_w : W_I_w) + j * (2 * DIM);
    const float* __restrict__ wR = W_R_w + j * DIM;

    float aSel = 0.f, aR = 0.f;
#pragma unroll 8
    for (int k = 0; k < DIM; ++k) {
        const float e = row[k];
        aSel += e * wSel[k];
        aR += e * wR[k];
    }
    R[t * DIM + j] = aSel + (fwd ? W_O_b[j] : W_I_b[j]);
    rel_new[t * DIM + j] = aR + W_R_b[j];
}

// ---------------------------------------------------------------------------
// Weight prep: merged WT[384][128] (row j: j<128 -> W_O ent-half row j;
// j<256 -> W_I ent-half; else W_S) split into bf16 hi/lo, plus bias384
// (0 for j<256, W_S_b else).
// ---------------------------------------------------------------------------
__global__ void __launch_bounds__(256)
wt_build_kernel(const float* __restrict__ W_O_w, const float* __restrict__ W_I_w,
                const float* __restrict__ W_S_w, const float* __restrict__ W_S_b,
                __bf16* __restrict__ WTh, __bf16* __restrict__ WTl,
                float* __restrict__ bias384) {
    const int idx = blockIdx.x * 256 + threadIdx.x;
    if (idx >= 384 * DIM) return;
    const int j = idx >> 7;
    const int k = idx & 127;
    float v;
    if (j < 128) v = W_O_w[j * (2 * DIM) + DIM + k];
    else if (j < 256) v = W_I_w[(j - 128) * (2 * DIM) + DIM + k];
    else v = W_S_w[(j - 256) * DIM + k];
    const __bf16 h = (__bf16)v;
    WTh[idx] = h;
    WTl[idx] = (__bf16)(v - (float)h);
    if (k == 0) bias384[j] = (j < 256) ? 0.f : W_S_b[j - 256];
}

// ---------------------------------------------------------------------------
// Kernel B (v6): MFMA bf16-split GEMM.  C[50000][384] = ent[50000][128] @ WT^T
// with fp32-equivalent accuracy via x = hi + lo (bf16) and
// acc += ah*bh + ah*bl + al*bh  (lo*lo term ~2^-18, negligible).
// One wave = 16 rows x 64 cols strip: 4 subtiles of 16x16, K swept in 4
// steps of 32 with mfma_f32_16x16x32_bf16.  A converted fp32->hi/lo
// in-register (no staging buffer).  Fragment k-addressing is identical for
// A and B, so any k-permutation in the HW layout cancels; C/D mapping is
// the m89-verified col=lane&15, row=(lane>>4)*4+reg.
// Col blocks (grid.y): 0,1 -> EE (W_O);  2,3 -> EE+N*DIM (W_I);
// 4,5 -> ent_S (W_S, +bias).
// ---------------------------------------------------------------------------
__global__ void __launch_bounds__(256)
mfma_gemm_kernel(const float* __restrict__ ent,
                 const __bf16* __restrict__ WTh, const __bf16* __restrict__ WTl,
                 const float* __restrict__ bias384,
                 float* __restrict__ EE, float* __restrict__ ent_S) {
    const int wave = threadIdx.x >> 6;
    const int rg = blockIdx.x * 4 + wave;  // 16-row group
    if (rg >= NROWG) return;
    const int l = threadIdx.x & 63;
    const int r16 = l & 15;   // row (A), col (B/D)
    const int kg = l >> 4;    // k-subgroup 0..3

    const int cb = blockIdx.y;       // 0..5
    const int c0 = cb * 64;          // global col base

    f32x4 acc0 = {0.f, 0.f, 0.f, 0.f};
    f32x4 acc1 = {0.f, 0.f, 0.f, 0.f};
    f32x4 acc2 = {0.f, 0.f, 0.f, 0.f};
    f32x4 acc3 = {0.f, 0.f, 0.f, 0.f};

    const int n = rg * 16 + r16;
    const float* __restrict__ aptr = ent + (size_t)n * DIM + kg * 8;
    const __bf16* __restrict__ b0 = WTh + (size_t)(c0 + 0 * 16 + r16) * DIM + kg * 8;
    const __bf16* __restrict__ b1 = WTh + (size_t)(c0 + 1 * 16 + r16) * DIM + kg * 8;
    const __bf16* __restrict__ b2 = WTh + (size_t)(c0 + 2 * 16 + r16) * DIM + kg * 8;
    const __bf16* __restrict__ b3 = WTh + (size_t)(c0 + 3 * 16 + r16) * DIM + kg * 8;
    const ptrdiff_t dlo = WTl - WTh;  // element offset between hi and lo tables

#pragma unroll
    for (int ks = 0; ks < 4; ++ks) {
        const float4 av0 = *(const float4*)(aptr + ks * 32);
        const float4 av1 = *(const float4*)(aptr + ks * 32 + 4);
        bf16x8 ah, al;
        {
            const float xs[8] = {av0.x, av0.y, av0.z, av0.w, av1.x, av1.y, av1.z, av1.w};
#pragma unroll
            for (int i = 0; i < 8; ++i) {
                const __bf16 h = (__bf16)xs[i];
                ah[i] = h;
                al[i] = (__bf16)(xs[i] - (float)h);
            }
        }
        const bf16x8 bh0 = *(const bf16x8*)(b0 + ks * 32);
        const bf16x8 bh1 = *(const bf16x8*)(b1 + ks * 32);
        const bf16x8 bh2 = *(const bf16x8*)(b2 + ks * 32);
        const bf16x8 bh3 = *(const bf16x8*)(b3 + ks * 32);
        const bf16x8 bl0 = *(const bf16x8*)(b0 + dlo + ks * 32);
        const bf16x8 bl1 = *(const bf16x8*)(b1 + dlo + ks * 32);
        const bf16x8 bl2 = *(const bf16x8*)(b2 + dlo + ks * 32);
        const bf16x8 bl3 = *(const bf16x8*)(b3 + dlo + ks * 32);

        acc0 = __builtin_amdgcn_mfma_f32_16x16x32_bf16(ah, bh0, acc0, 0, 0, 0);
        acc1 = __builtin_amdgcn_mfma_f32_16x16x32_bf16(ah, bh1, acc1, 0, 0, 0);
        acc2 = __builtin_amdgcn_mfma_f32_16x16x32_bf16(ah, bh2, acc2, 0, 0, 0);
        acc3 = __builtin_amdgcn_mfma_f32_16x16x32_bf16(ah, bh3, acc3, 0, 0, 0);
        acc0 = __builtin_amdgcn_mfma_f32_16x16x32_bf16(al, bh0, acc0, 0, 0, 0);
        acc1 = __builtin_amdgcn_mfma_f32_16x16x32_bf16(al, bh1, acc1, 0, 0, 0);
        acc2 = __builtin_amdgcn_mfma_f32_16x16x32_bf16(al, bh2, acc2, 0, 0, 0);
        acc3 = __builtin_amdgcn_mfma_f32_16x16x32_bf16(al, bh3, acc3, 0, 0, 0);
        acc0 = __builtin_amdgcn_mfma_f32_16x16x32_bf16(ah, bl0, acc0, 0, 0, 0);
        acc1 = __builtin_amdgcn_mfma_f32_16x16x32_bf16(ah, bl1, acc1, 0, 0, 0);
        acc2 = __builtin_amdgcn_mfma_f32_16x16x32_bf16(ah, bl2, acc2, 0, 0, 0);
        acc3 = __builtin_amdgcn_mfma_f32_16x16x32_bf16(ah, bl3, acc3, 0, 0, 0);
    }

    // Epilogue: D[row=(l>>4)*4+r][col=l&15] per 16x16 subtile.
    float* obase;
    if (cb < 2) obase = EE;
    else if (cb < 4) obase = EE + (size_t)N_NODES * DIM;
    else obase = ent_S;
    const int jloc0 = c0 & 127;

#define EPI(s, ACC)                                                           \
    {                                                                         \
        const int col = jloc0 + (s) * 16 + r16;                               \
        const float bs = bias384[c0 + (s) * 16 + r16];                        \
        const int orow = rg * 16 + kg * 4;                                    \
        obase[(size_t)(orow + 0) * DIM + col] = ACC[0] + bs;                  \
        obase[(size_t)(orow + 1) * DIM + col] = ACC[1] + bs;                  \
        obase[(size_t)(orow + 2) * DIM + col] = ACC[2] + bs;                  \
        obase[(size_t)(orow + 3) * DIM + col] = ACC[3] + bs;                  \
    }
    EPI(0, acc0)
    EPI(1, acc1)
    EPI(2, acc2)
    EPI(3, acc3)
#undef EPI
}

// ---------------------------------------------------------------------------
// CSR construction: histogram -> 3-phase exclusive scan -> fill.
// ---------------------------------------------------------------------------
__global__ void __launch_bounds__(256)
hist_kernel(const int* __restrict__ dst, int* __restrict__ counts) {
    const int e = blockIdx.x * 256 + threadIdx.x;
    if (e < N_EDGES) atomicAdd(&counts[dst[e]], 1);
}

__global__ void __launch_bounds__(SCAN_BLK)
scan1_kernel(const int* __restrict__ counts, int* __restrict__ offs,
             int* __restrict__ bsum) {
    __shared__ int tmp[SCAN_BLK];
    const int i = blockIdx.x * SCAN_BLK + threadIdx.x;
    const int v = (i < N_NODES) ? counts[i] : 0;
    tmp[threadIdx.x] = v;
    __syncthreads();
    for (int off = 1; off < SCAN_BLK; off <<= 1) {
        const int t = (threadIdx.x >= off) ? tmp[threadIdx.x - off] : 0;
        __syncthreads();
        tmp[threadIdx.x] += t;
        __syncthreads();
    }
    if (i < N_NODES) offs[i] = tmp[threadIdx.x] - v;  // exclusive
    if (threadIdx.x == SCAN_BLK - 1) bsum[blockIdx.x] = tmp[SCAN_BLK - 1];
}

__global__ void __launch_bounds__(128)
scan2_kernel(int* __restrict__ bsum) {
    __shared__ int tmp[128];
    const int i = threadIdx.x;
    const int v = (i < SCAN_NBLK) ? bsum[i] : 0;
    tmp[i] = v;
    __syncthreads();
    for (int off = 1; off < 128; off <<= 1) {
        const int tv = (i >= off) ? tmp[i - off] : 0;
        __syncthreads();
        tmp[i] += tv;
        __syncthreads();
    }
    if (i < SCAN_NBLK) bsum[i] = tmp[i] - v;  // exclusive
}

__global__ void __launch_bounds__(SCAN_BLK)
scan3_kernel(int* __restrict__ offs, const int* __restrict__ bsum) {
    const int i = blockIdx.x * SCAN_BLK + threadIdx.x;
    if (i < N_NODES) offs[i] += bsum[blockIdx.x];
}

// Fill: sorted-by-dst packed edge payload: row(17b) | etype<<17 (9b).
__global__ void __launch_bounds__(256)
fill_kernel(const int* __restrict__ src, const int* __restrict__ dst,
            const int* __restrict__ et, const int* __restrict__ offs,
            int* __restrict__ cursor, int* __restrict__ sp) {
    const int e = blockIdx.x * 256 + threadIdx.x;
    if (e >= N_EDGES) return;
    const int d = dst[e];
    const int t = et[e];
    const int row = src[e] + ((t < NUM_REL) ? 0 : N_NODES);
    const int pos = atomicAdd(&cursor[d], 1);
    sp[offs[d] + pos] = row | (t << 17);
}

// ---------------------------------------------------------------------------
// Gather-reduce: one wave per node. Lane l owns output floats [2l, 2l+1].
// Fuses finalize: out = ent_S + acc / max(deg,1).  (Unchanged — its counters
// surface next round once the GEMM shrinks.)
// ---------------------------------------------------------------------------
__global__ void __launch_bounds__(256)
gather_kernel(const int* __restrict__ offs, const int* __restrict__ counts,
              const int* __restrict__ sp, const float* __restrict__ EE,
              const float* __restrict__ R, const float* __restrict__ ent_S,
              float* __restrict__ out_ent) {
    const int node = blockIdx.x * 4 + (threadIdx.x >> 6);
    if (node >= N_NODES) return;
    const int l = threadIdx.x & 63;

    const int beg = offs[node];
    const int cnt = counts[node];

    float ax = 0.f, ay = 0.f;
    for (int base = 0; base < cnt; base += 64) {
        const int kk = min(64, cnt - base);
        const int myp = (base + l < cnt) ? sp[beg + base + l] : 0;
#pragma unroll 4
        for (int i = 0; i < kk; ++i) {
            const int p = __shfl(myp, i);
            const int row = p & 0x1FFFF;
            const int t = p >> 17;
            const float2 e = *(const float2*)(EE + (size_t)row * DIM + 2 * l);
            const float2 r = *(const float2*)(R + (size_t)t * DIM + 2 * l);
            ax += e.x + r.x;
            ay += e.y + r.y;
        }
    }

    const float inv = 1.0f / fmaxf((float)cnt, 1.0f);
    const float2 s = *(const float2*)(ent_S + (size_t)node * DIM + 2 * l);
    float2 o;
    o.x = s.x + ax * inv;
    o.y = s.y + ay * inv;
    *(float2*)(out_ent + (size_t)node * DIM + 2 * l) = o;
}

extern "C" void kernel_launch(void* const* d_in, const int* in_sizes, int n_in,
                              void* d_out, int out_size, void* d_ws, size_t ws_size,
                              hipStream_t stream) {
    const int* src = (const int*)d_in[0];
    const int* dst = (const int*)d_in[1];
    const int* et = (const int*)d_in[2];
    const float* ent_emb = (const float*)d_in[3];
    const float* rel_emb = (const float*)d_in[4];
    const float* W_O_w = (const float*)d_in[5];
    const float* W_O_b = (const float*)d_in[6];
    const float* W_I_w = (const float*)d_in[7];
    const float* W_I_b = (const float*)d_in[8];
    const float* W_S_w = (const float*)d_in[9];
    const float* W_S_b = (const float*)d_in[10];
    const float* W_R_w = (const float*)d_in[11];
    const float* W_R_b = (const float*)d_in[12];

    float* out_ent = (float*)d_out;                    // [50000*128]
    float* out_rel = out_ent + (size_t)N_NODES * DIM;  // [400*128]

    // Workspace layout (floats):
    // R | EE | ent_S | WTh | WTl | bias384 | counts,cursor | bsum | offs | sp
    float* wsf = (float*)d_ws;
    float* R = wsf;
    wsf += (size_t)NREL2 * DIM;          // 51,200 f
    float* EE = wsf;
    wsf += (size_t)2 * N_NODES * DIM;    // 12.8M f
    float* ent_S = wsf;
    wsf += (size_t)N_NODES * DIM;        // 6.4M f
    __bf16* WTh = (__bf16*)wsf;
    wsf += 384 * DIM / 2;                // 49152 bf16 = 24576 f
    __bf16* WTl = (__bf16*)wsf;
    wsf += 384 * DIM / 2;
    float* bias384 = wsf;
    wsf += 384;
    int* counts = (int*)wsf;
    int* cursor = counts + N_NODES;
    int* bsum = cursor + N_NODES;
    int* offs = bsum + 128;
    int* sp = offs + N_NODES;
    // total ~81 MB

    hipMemsetAsync(counts, 0, 2 * N_NODES * sizeof(int), stream);

    rel_tables_kernel<<<NREL2, DIM, 0, stream>>>(rel_emb, W_O_w, W_O_b, W_I_w, W_I_b,
                                                 W_R_w, W_R_b, R, out_rel);

    wt_build_kernel<<<(384 * DIM + 255) / 256, 256, 0, stream>>>(
        W_O_w, W_I_w, W_S_w, W_S_b, WTh, WTl, bias384);

    mfma_gemm_kernel<<<dim3((NROWG + 3) / 4, 6), 256, 0, stream>>>(
        ent_emb, WTh, WTl, bias384, EE, ent_S);

    hist_kernel<<<(N_EDGES + 255) / 256, 256, 0, stream>>>(dst, counts);
    scan1_kernel<<<SCAN_NBLK, SCAN_BLK, 0, stream>>>(counts, offs, bsum);
    scan2_kernel<<<1, 128, 0, stream>>>(bsum);
    scan3_kernel<<<SCAN_NBLK, SCAN_BLK, 0, stream>>>(offs, bsum);
    fill_kernel<<<(N_EDGES + 255) / 256, 256, 0, stream>>>(src, dst, et, offs, cursor, sp);

    gather_kernel<<<(N_NODES + 3) / 4, 256, 0, stream>>>(offs, counts, sp, EE, R, ent_S,
                                                         out_ent);
}

// Round 7
// 267.427 us; speedup vs baseline: 1.2539x; 1.0155x over previous
//
#include <hip/hip_runtime.h>
#include <hip/hip_bf16.h>

#define N_NODES 50000
#define N_EDGES 800000
#define DIM 128
#define NUM_REL 200
#define NREL2 (2 * NUM_REL)
#define SCAN_BLK 512
#define SCAN_NBLK ((N_NODES + SCAN_BLK - 1) / SCAN_BLK)  // 98
#define NROWG (N_NODES / 16)  // 3125 row groups of 16 nodes

typedef __bf16 bf16x8 __attribute__((ext_vector_type(8)));
typedef float f32x4 __attribute__((ext_vector_type(4)));

// ---------------------------------------------------------------------------
// Kernel A: merged relation table R[400][128] (W_O rel-half for t<200, W_I
// rel-half else, + matching bias) and rel_new output (rel_emb @ W_R^T + b_R).
// ---------------------------------------------------------------------------
__global__ void rel_tables_kernel(const float* __restrict__ rel_emb,
                                  const float* __restrict__ W_O_w,
                                  const float* __restrict__ W_O_b,
                                  const float* __restrict__ W_I_w,
                                  const float* __restrict__ W_I_b,
                                  const float* __restrict__ W_R_w,
                                  const float* __restrict__ W_R_b,
                                  float* __restrict__ R,
                                  float* __restrict__ rel_new) {
    __shared__ float row[DIM];
    const int t = blockIdx.x;   // 0..399
    const int j = threadIdx.x;  // 0..127
    row[j] = rel_emb[t * DIM + j];
    __syncthreads();

    const bool fwd = (t < NUM_REL);
    const float* __restrict__ wSel = (fwd ? W_O_w : W_I_w) + j * (2 * DIM);
    const float* __restrict__ wR = W_R_w + j * DIM;

    float aSel = 0.f, aR = 0.f;
#pragma unroll 8
    for (int k = 0; k < DIM; ++k) {
        const float e = row[k];
        aSel += e * wSel[k];
        aR += e * wR[k];
    }
    R[t * DIM + j] = aSel + (fwd ? W_O_b[j] : W_I_b[j]);
    rel_new[t * DIM + j] = aR + W_R_b[j];
}

// ---------------------------------------------------------------------------
// Weight prep: merged WT[384][128] (row j: j<128 -> W_O ent-half row j;
// j<256 -> W_I ent-half; else W_S) split into bf16 hi/lo.
// ---------------------------------------------------------------------------
__global__ void __launch_bounds__(256)
wt_build_kernel(const float* __restrict__ W_O_w, const float* __restrict__ W_I_w,
                const float* __restrict__ W_S_w,
                __bf16* __restrict__ WTh, __bf16* __restrict__ WTl) {
    const int idx = blockIdx.x * 256 + threadIdx.x;
    if (idx >= 384 * DIM) return;
    const int j = idx >> 7;
    const int k = idx & 127;
    float v;
    if (j < 128) v = W_O_w[j * (2 * DIM) + DIM + k];
    else if (j < 256) v = W_I_w[(j - 128) * (2 * DIM) + DIM + k];
    else v = W_S_w[(j - 256) * DIM + k];
    const __bf16 h = (__bf16)v;
    WTh[idx] = h;
    WTl[idx] = (__bf16)(v - (float)h);
}

// ---------------------------------------------------------------------------
// Kernel B (v7): single-pass MFMA bf16-split GEMM.
// C[50000][384] = ent[50000][128] @ WT^T, fp32-ish accuracy via hi/lo split
// (keep ah*bh + al*bh + ah*bl).  One wave = 16 rows; A is loaded ONCE,
// converted to hi/lo bf16 fragments held in registers (32 VGPR), then all
// 6 column-blocks (24 16x16 subtiles) are computed re-using them ->
// A fetched exactly once (FETCH ~26MB vs v6's 76MB), B (196KB) L1/L2-hot.
// Outputs: cols 0..255 -> EEb (bf16!), cols 256..383 -> ent_S (fp32, +b_S).
// ---------------------------------------------------------------------------
#define REP4(F) F(0) F(1) F(2) F(3)

__global__ void __launch_bounds__(256)
mfma_gemm_kernel(const float* __restrict__ ent,
                 const __bf16* __restrict__ WTh, const __bf16* __restrict__ WTl,
                 const float* __restrict__ W_S_b,
                 __bf16* __restrict__ EEb, float* __restrict__ ent_S) {
    const int wave = threadIdx.x >> 6;
    const int rg = blockIdx.x * 4 + wave;  // 16-row group
    if (rg >= NROWG) return;
    const int l = threadIdx.x & 63;
    const int r16 = l & 15;  // row (A) / col (B,D)
    const int kg = l >> 4;   // k-subgroup 0..3

    // ---- Load & convert A fragments once: ah0..3 / al0..3 (bf16x8 each) ----
    const float* __restrict__ aptr = ent + (size_t)(rg * 16 + r16) * DIM + kg * 8;
#define ADECL(ks)                                                              \
    bf16x8 ah##ks, al##ks;                                                     \
    {                                                                          \
        const float4 v0 = *(const float4*)(aptr + (ks) * 32);                  \
        const float4 v1 = *(const float4*)(aptr + (ks) * 32 + 4);              \
        const float xs[8] = {v0.x, v0.y, v0.z, v0.w, v1.x, v1.y, v1.z, v1.w};  \
        _Pragma("unroll") for (int i = 0; i < 8; ++i) {                        \
            const __bf16 h = (__bf16)xs[i];                                    \
            ah##ks[i] = h;                                                     \
            al##ks[i] = (__bf16)(xs[i] - (float)h);                            \
        }                                                                      \
    }
    REP4(ADECL)
#undef ADECL

    const ptrdiff_t dlo = WTl - WTh;  // element offset hi -> lo table
    const int orow = rg * 16 + kg * 4;

#pragma unroll
    for (int cb = 0; cb < 6; ++cb) {
        const int c0 = cb * 64;
        const __bf16* __restrict__ bb = WTh + (size_t)(c0 + r16) * DIM + kg * 8;

        f32x4 acc0 = {0.f, 0.f, 0.f, 0.f};
        f32x4 acc1 = {0.f, 0.f, 0.f, 0.f};
        f32x4 acc2 = {0.f, 0.f, 0.f, 0.f};
        f32x4 acc3 = {0.f, 0.f, 0.f, 0.f};

#define KSTEP(ks)                                                              \
    {                                                                          \
        const bf16x8 bh0 = *(const bf16x8*)(bb + (size_t)0 * 16 * DIM + (ks) * 32);  \
        const bf16x8 bh1 = *(const bf16x8*)(bb + (size_t)1 * 16 * DIM + (ks) * 32);  \
        const bf16x8 bh2 = *(const bf16x8*)(bb + (size_t)2 * 16 * DIM + (ks) * 32);  \
        const bf16x8 bh3 = *(const bf16x8*)(bb + (size_t)3 * 16 * DIM + (ks) * 32);  \
        const bf16x8 bl0 = *(const bf16x8*)(bb + dlo + (size_t)0 * 16 * DIM + (ks) * 32); \
        const bf16x8 bl1 = *(const bf16x8*)(bb + dlo + (size_t)1 * 16 * DIM + (ks) * 32); \
        const bf16x8 bl2 = *(const bf16x8*)(bb + dlo + (size_t)2 * 16 * DIM + (ks) * 32); \
        const bf16x8 bl3 = *(const bf16x8*)(bb + dlo + (size_t)3 * 16 * DIM + (ks) * 32); \
        acc0 = __builtin_amdgcn_mfma_f32_16x16x32_bf16(ah##ks, bh0, acc0, 0, 0, 0); \
        acc1 = __builtin_amdgcn_mfma_f32_16x16x32_bf16(ah##ks, bh1, acc1, 0, 0, 0); \
        acc2 = __builtin_amdgcn_mfma_f32_16x16x32_bf16(ah##ks, bh2, acc2, 0, 0, 0); \
        acc3 = __builtin_amdgcn_mfma_f32_16x16x32_bf16(ah##ks, bh3, acc3, 0, 0, 0); \
        acc0 = __builtin_amdgcn_mfma_f32_16x16x32_bf16(al##ks, bh0, acc0, 0, 0, 0); \
        acc1 = __builtin_amdgcn_mfma_f32_16x16x32_bf16(al##ks, bh1, acc1, 0, 0, 0); \
        acc2 = __builtin_amdgcn_mfma_f32_16x16x32_bf16(al##ks, bh2, acc2, 0, 0, 0); \
        acc3 = __builtin_amdgcn_mfma_f32_16x16x32_bf16(al##ks, bh3, acc3, 0, 0, 0); \
        acc0 = __builtin_amdgcn_mfma_f32_16x16x32_bf16(ah##ks, bl0, acc0, 0, 0, 0); \
        acc1 = __builtin_amdgcn_mfma_f32_16x16x32_bf16(ah##ks, bl1, acc1, 0, 0, 0); \
        acc2 = __builtin_amdgcn_mfma_f32_16x16x32_bf16(ah##ks, bl2, acc2, 0, 0, 0); \
        acc3 = __builtin_amdgcn_mfma_f32_16x16x32_bf16(ah##ks, bl3, acc3, 0, 0, 0); \
    }
        REP4(KSTEP)
#undef KSTEP

        // ---- Epilogue for this column block ----
        const int colb = (cb & 1) * 64;  // col base within the 128-wide output
        if (cb < 4) {
            __bf16* __restrict__ ob = EEb + ((cb < 2) ? 0 : (size_t)N_NODES * DIM);
#define ST(s, ACC)                                                             \
            {                                                                  \
                const int col = colb + (s) * 16 + r16;                         \
                ob[(size_t)(orow + 0) * DIM + col] = (__bf16)ACC[0];           \
                ob[(size_t)(orow + 1) * DIM + col] = (__bf16)ACC[1];           \
                ob[(size_t)(orow + 2) * DIM + col] = (__bf16)ACC[2];           \
                ob[(size_t)(orow + 3) * DIM + col] = (__bf16)ACC[3];           \
            }
            ST(0, acc0) ST(1, acc1) ST(2, acc2) ST(3, acc3)
#undef ST
        } else {
#define ST(s, ACC)                                                             \
            {                                                                  \
                const int col = colb + (s) * 16 + r16;                         \
                const float bs = W_S_b[col];                                   \
                ent_S[(size_t)(orow + 0) * DIM + col] = ACC[0] + bs;           \
                ent_S[(size_t)(orow + 1) * DIM + col] = ACC[1] + bs;           \
                ent_S[(size_t)(orow + 2) * DIM + col] = ACC[2] + bs;           \
                ent_S[(size_t)(orow + 3) * DIM + col] = ACC[3] + bs;           \
            }
            ST(0, acc0) ST(1, acc1) ST(2, acc2) ST(3, acc3)
#undef ST
        }
    }
}

// ---------------------------------------------------------------------------
// CSR construction: histogram -> 3-phase exclusive scan -> fill.
// ---------------------------------------------------------------------------
__global__ void __launch_bounds__(256)
hist_kernel(const int* __restrict__ dst, int* __restrict__ counts) {
    const int e = blockIdx.x * 256 + threadIdx.x;
    if (e < N_EDGES) atomicAdd(&counts[dst[e]], 1);
}

__global__ void __launch_bounds__(SCAN_BLK)
scan1_kernel(const int* __restrict__ counts, int* __restrict__ offs,
             int* __restrict__ bsum) {
    __shared__ int tmp[SCAN_BLK];
    const int i = blockIdx.x * SCAN_BLK + threadIdx.x;
    const int v = (i < N_NODES) ? counts[i] : 0;
    tmp[threadIdx.x] = v;
    __syncthreads();
    for (int off = 1; off < SCAN_BLK; off <<= 1) {
        const int t = (threadIdx.x >= off) ? tmp[threadIdx.x - off] : 0;
        __syncthreads();
        tmp[threadIdx.x] += t;
        __syncthreads();
    }
    if (i < N_NODES) offs[i] = tmp[threadIdx.x] - v;  // exclusive
    if (threadIdx.x == SCAN_BLK - 1) bsum[blockIdx.x] = tmp[SCAN_BLK - 1];
}

__global__ void __launch_bounds__(128)
scan2_kernel(int* __restrict__ bsum) {
    __shared__ int tmp[128];
    const int i = threadIdx.x;
    const int v = (i < SCAN_NBLK) ? bsum[i] : 0;
    tmp[i] = v;
    __syncthreads();
    for (int off = 1; off < 128; off <<= 1) {
        const int tv = (i >= off) ? tmp[i - off] : 0;
        __syncthreads();
        tmp[i] += tv;
        __syncthreads();
    }
    if (i < SCAN_NBLK) bsum[i] = tmp[i] - v;  // exclusive
}

__global__ void __launch_bounds__(SCAN_BLK)
scan3_kernel(int* __restrict__ offs, const int* __restrict__ bsum) {
    const int i = blockIdx.x * SCAN_BLK + threadIdx.x;
    if (i < N_NODES) offs[i] += bsum[blockIdx.x];
}

// Fill: sorted-by-dst packed edge payload: row(17b) | etype<<17 (9b).
__global__ void __launch_bounds__(256)
fill_kernel(const int* __restrict__ src, const int* __restrict__ dst,
            const int* __restrict__ et, const int* __restrict__ offs,
            int* __restrict__ cursor, int* __restrict__ sp) {
    const int e = blockIdx.x * 256 + threadIdx.x;
    if (e >= N_EDGES) return;
    const int d = dst[e];
    const int t = et[e];
    const int row = src[e] + ((t < NUM_REL) ? 0 : N_NODES);
    const int pos = atomicAdd(&cursor[d], 1);
    sp[offs[d] + pos] = row | (t << 17);
}

// ---------------------------------------------------------------------------
// Gather-reduce: one wave per node. Lane l owns output floats [2l, 2l+1].
// EEb is bf16 (half the L3 traffic of fp32); accumulate in fp32.
// Fuses finalize: out = ent_S + acc / max(deg,1).
// ---------------------------------------------------------------------------
__global__ void __launch_bounds__(256)
gather_kernel(const int* __restrict__ offs, const int* __restrict__ counts,
              const int* __restrict__ sp, const __bf16* __restrict__ EEb,
              const float* __restrict__ R, const float* __restrict__ ent_S,
              float* __restrict__ out_ent) {
    const int node = blockIdx.x * 4 + (threadIdx.x >> 6);
    if (node >= N_NODES) return;
    const int l = threadIdx.x & 63;

    const int beg = offs[node];
    const int cnt = counts[node];

    float ax = 0.f, ay = 0.f;
    for (int base = 0; base < cnt; base += 64) {
        const int kk = min(64, cnt - base);
        const int myp = (base + l < cnt) ? sp[beg + base + l] : 0;
#pragma unroll 4
        for (int i = 0; i < kk; ++i) {
            const int p = __shfl(myp, i);
            const int row = p & 0x1FFFF;
            const int t = p >> 17;
            const unsigned int v = *(const unsigned int*)(EEb + (size_t)row * DIM + 2 * l);
            const float ex = __uint_as_float((v & 0xffffu) << 16);
            const float ey = __uint_as_float(v & 0xffff0000u);
            const float2 r = *(const float2*)(R + (size_t)t * DIM + 2 * l);
            ax += ex + r.x;
            ay += ey + r.y;
        }
    }

    const float inv = 1.0f / fmaxf((float)cnt, 1.0f);
    const float2 s = *(const float2*)(ent_S + (size_t)node * DIM + 2 * l);
    float2 o;
    o.x = s.x + ax * inv;
    o.y = s.y + ay * inv;
    *(float2*)(out_ent + (size_t)node * DIM + 2 * l) = o;
}

extern "C" void kernel_launch(void* const* d_in, const int* in_sizes, int n_in,
                              void* d_out, int out_size, void* d_ws, size_t ws_size,
                              hipStream_t stream) {
    const int* src = (const int*)d_in[0];
    const int* dst = (const int*)d_in[1];
    const int* et = (const int*)d_in[2];
    const float* ent_emb = (const float*)d_in[3];
    const float* rel_emb = (const float*)d_in[4];
    const float* W_O_w = (const float*)d_in[5];
    const float* W_O_b = (const float*)d_in[6];
    const float* W_I_w = (const float*)d_in[7];
    const float* W_I_b = (const float*)d_in[8];
    const float* W_S_w = (const float*)d_in[9];
    const float* W_S_b = (const float*)d_in[10];
    const float* W_R_w = (const float*)d_in[11];
    const float* W_R_b = (const float*)d_in[12];

    float* out_ent = (float*)d_out;                    // [50000*128]
    float* out_rel = out_ent + (size_t)N_NODES * DIM;  // [400*128]

    // Workspace layout (floats):
    // R | ent_S | EEb(bf16) | WTh | WTl | counts,cursor | bsum | offs | sp
    float* wsf = (float*)d_ws;
    float* R = wsf;
    wsf += (size_t)NREL2 * DIM;          // 51,200 f
    float* ent_S = wsf;
    wsf += (size_t)N_NODES * DIM;        // 6.4M f
    __bf16* EEb = (__bf16*)wsf;
    wsf += (size_t)N_NODES * DIM;        // 12.8M bf16 = 6.4M f
    __bf16* WTh = (__bf16*)wsf;
    wsf += 384 * DIM / 2;
    __bf16* WTl = (__bf16*)wsf;
    wsf += 384 * DIM / 2;
    int* counts = (int*)wsf;
    int* cursor = counts + N_NODES;
    int* bsum = cursor + N_NODES;
    int* offs = bsum + 128;
    int* sp = offs + N_NODES;
    // total ~56 MB

    hipMemsetAsync(counts, 0, 2 * N_NODES * sizeof(int), stream);

    rel_tables_kernel<<<NREL2, DIM, 0, stream>>>(rel_emb, W_O_w, W_O_b, W_I_w, W_I_b,
                                                 W_R_w, W_R_b, R, out_rel);

    wt_build_kernel<<<(384 * DIM + 255) / 256, 256, 0, stream>>>(
        W_O_w, W_I_w, W_S_w, WTh, WTl);

    mfma_gemm_kernel<<<(NROWG + 3) / 4, 256, 0, stream>>>(
        ent_emb, WTh, WTl, W_S_b, EEb, ent_S);

    hist_kernel<<<(N_EDGES + 255) / 256, 256, 0, stream>>>(dst, counts);
    scan1_kernel<<<SCAN_NBLK, SCAN_BLK, 0, stream>>>(counts, offs, bsum);
    scan2_kernel<<<1, 128, 0, stream>>>(bsum);
    scan3_kernel<<<SCAN_NBLK, SCAN_BLK, 0, stream>>>(offs, bsum);
    fill_kernel<<<(N_EDGES + 255) / 256, 256, 0, stream>>>(src, dst, et, offs, cursor, sp);

    gather_kernel<<<(N_NODES + 3) / 4, 256, 0, stream>>>(offs, counts, sp, EEb, R, ent_S,
                                                         out_ent);
}

// Round 8
// 259.116 us; speedup vs baseline: 1.2941x; 1.0321x over previous
//
#include <hip/hip_runtime.h>
#include <hip/hip_bf16.h>

#define N_NODES 50000
#define N_EDGES 800000
#define DIM 128
#define NUM_REL 200
#define NREL2 (2 * NUM_REL)
#define SCAN_BLK 512
#define SCAN_NBLK ((N_NODES + SCAN_BLK - 1) / SCAN_BLK)  // 98
#define NROWG (N_NODES / 16)  // 3125 row groups of 16 nodes

typedef __bf16 bf16x8 __attribute__((ext_vector_type(8)));
typedef float f32x4 __attribute__((ext_vector_type(4)));

// ---------------------------------------------------------------------------
// Kernel A: merged relation table R[400][128] (W_O rel-half for t<200, W_I
// rel-half else, + matching bias) and rel_new output (rel_emb @ W_R^T + b_R).
// ---------------------------------------------------------------------------
__global__ void rel_tables_kernel(const float* __restrict__ rel_emb,
                                  const float* __restrict__ W_O_w,
                                  const float* __restrict__ W_O_b,
                                  const float* __restrict__ W_I_w,
                                  const float* __restrict__ W_I_b,
                                  const float* __restrict__ W_R_w,
                                  const float* __restrict__ W_R_b,
                                  float* __restrict__ R,
                                  float* __restrict__ rel_new) {
    __shared__ float row[DIM];
    const int t = blockIdx.x;   // 0..399
    const int j = threadIdx.x;  // 0..127
    row[j] = rel_emb[t * DIM + j];
    __syncthreads();

    const bool fwd = (t < NUM_REL);
    const float* __restrict__ wSel = (fwd ? W_O_w : W_I_w) + j * (2 * DIM);
    const float* __restrict__ wR = W_R_w + j * DIM;

    float aSel = 0.f, aR = 0.f;
#pragma unroll 8
    for (int k = 0; k < DIM; ++k) {
        const float e = row[k];
        aSel += e * wSel[k];
        aR += e * wR[k];
    }
    R[t * DIM + j] = aSel + (fwd ? W_O_b[j] : W_I_b[j]);
    rel_new[t * DIM + j] = aR + W_R_b[j];
}

// ---------------------------------------------------------------------------
// Weight prep: merged WT[384][128] (row j: j<128 -> W_O ent-half row j;
// j<256 -> W_I ent-half; else W_S) split into bf16 hi/lo.
// ---------------------------------------------------------------------------
__global__ void __launch_bounds__(256)
wt_build_kernel(const float* __restrict__ W_O_w, const float* __restrict__ W_I_w,
                const float* __restrict__ W_S_w,
                __bf16* __restrict__ WTh, __bf16* __restrict__ WTl) {
    const int idx = blockIdx.x * 256 + threadIdx.x;
    if (idx >= 384 * DIM) return;
    const int j = idx >> 7;
    const int k = idx & 127;
    float v;
    if (j < 128) v = W_O_w[j * (2 * DIM) + DIM + k];
    else if (j < 256) v = W_I_w[(j - 128) * (2 * DIM) + DIM + k];
    else v = W_S_w[(j - 256) * DIM + k];
    const __bf16 h = (__bf16)v;
    WTh[idx] = h;
    WTl[idx] = (__bf16)(v - (float)h);
}

// ---------------------------------------------------------------------------
// Kernel B (v8): MFMA bf16-split GEMM, latency-optimized.
// C[50000][384] = ent[50000][128] @ WT^T via hi/lo split (hh + lh + hl).
// Wave = 16 rows x 192 cols (3 column blocks); 2 waves per row-group ->
// 6256 waves (24/CU, 2x v7).  Per column block, 12 INDEPENDENT accumulator
// chains (hh/lh/hl x 4 subtiles, chain length 4) instead of v7's 4 chains
// of length 12 -> 3x the MFMA ILP to hide B-load latency.  A loaded and
// converted once per wave (A fetched 2x total).
// Outputs: cols 0..255 -> EEb (bf16), cols 256..383 -> ent_S (fp32, +b_S).
// ---------------------------------------------------------------------------
#define REP4(F) F(0) F(1) F(2) F(3)

__global__ void __launch_bounds__(256)
mfma_gemm_kernel(const float* __restrict__ ent,
                 const __bf16* __restrict__ WTh, const __bf16* __restrict__ WTl,
                 const float* __restrict__ W_S_b,
                 __bf16* __restrict__ EEb, float* __restrict__ ent_S) {
    const int w = threadIdx.x >> 6;
    const int rg = blockIdx.x * 2 + (w >> 1);  // 16-row group
    if (rg >= NROWG) return;
    const int half = w & 1;  // 0: cols 0..191, 1: cols 192..383
    const int l = threadIdx.x & 63;
    const int r16 = l & 15;  // row (A) / col (B,D)
    const int kg = l >> 4;   // k-subgroup 0..3

    // ---- Load & convert A fragments once: ah0..3 / al0..3 (bf16x8 each) ----
    const float* __restrict__ aptr = ent + (size_t)(rg * 16 + r16) * DIM + kg * 8;
#define ADECL(ks)                                                              \
    bf16x8 ah##ks, al##ks;                                                     \
    {                                                                          \
        const float4 v0 = *(const float4*)(aptr + (ks) * 32);                  \
        const float4 v1 = *(const float4*)(aptr + (ks) * 32 + 4);              \
        const float xs[8] = {v0.x, v0.y, v0.z, v0.w, v1.x, v1.y, v1.z, v1.w};  \
        _Pragma("unroll") for (int i = 0; i < 8; ++i) {                        \
            const __bf16 h = (__bf16)xs[i];                                    \
            ah##ks[i] = h;                                                     \
            al##ks[i] = (__bf16)(xs[i] - (float)h);                            \
        }                                                                      \
    }
    REP4(ADECL)
#undef ADECL

    const ptrdiff_t dlo = WTl - WTh;  // element offset hi -> lo table
    const int orow = rg * 16 + kg * 4;

#pragma unroll 1
    for (int cbi = 0; cbi < 3; ++cbi) {
        const int cb = half * 3 + cbi;   // 0..5
        const int c0 = cb * 64;
        const __bf16* __restrict__ bb = WTh + (size_t)(c0 + r16) * DIM + kg * 8;

        f32x4 hh0 = {0.f, 0.f, 0.f, 0.f}, hh1 = {0.f, 0.f, 0.f, 0.f};
        f32x4 hh2 = {0.f, 0.f, 0.f, 0.f}, hh3 = {0.f, 0.f, 0.f, 0.f};
        f32x4 lh0 = {0.f, 0.f, 0.f, 0.f}, lh1 = {0.f, 0.f, 0.f, 0.f};
        f32x4 lh2 = {0.f, 0.f, 0.f, 0.f}, lh3 = {0.f, 0.f, 0.f, 0.f};
        f32x4 hl0 = {0.f, 0.f, 0.f, 0.f}, hl1 = {0.f, 0.f, 0.f, 0.f};
        f32x4 hl2 = {0.f, 0.f, 0.f, 0.f}, hl3 = {0.f, 0.f, 0.f, 0.f};

#define KSTEP(ks)                                                              \
    {                                                                          \
        const bf16x8 bh0 = *(const bf16x8*)(bb + (size_t)0 * 16 * DIM + (ks) * 32);  \
        const bf16x8 bh1 = *(const bf16x8*)(bb + (size_t)1 * 16 * DIM + (ks) * 32);  \
        const bf16x8 bh2 = *(const bf16x8*)(bb + (size_t)2 * 16 * DIM + (ks) * 32);  \
        const bf16x8 bh3 = *(const bf16x8*)(bb + (size_t)3 * 16 * DIM + (ks) * 32);  \
        const bf16x8 bl0 = *(const bf16x8*)(bb + dlo + (size_t)0 * 16 * DIM + (ks) * 32); \
        const bf16x8 bl1 = *(const bf16x8*)(bb + dlo + (size_t)1 * 16 * DIM + (ks) * 32); \
        const bf16x8 bl2 = *(const bf16x8*)(bb + dlo + (size_t)2 * 16 * DIM + (ks) * 32); \
        const bf16x8 bl3 = *(const bf16x8*)(bb + dlo + (size_t)3 * 16 * DIM + (ks) * 32); \
        hh0 = __builtin_amdgcn_mfma_f32_16x16x32_bf16(ah##ks, bh0, hh0, 0, 0, 0); \
        hh1 = __builtin_amdgcn_mfma_f32_16x16x32_bf16(ah##ks, bh1, hh1, 0, 0, 0); \
        hh2 = __builtin_amdgcn_mfma_f32_16x16x32_bf16(ah##ks, bh2, hh2, 0, 0, 0); \
        hh3 = __builtin_amdgcn_mfma_f32_16x16x32_bf16(ah##ks, bh3, hh3, 0, 0, 0); \
        lh0 = __builtin_amdgcn_mfma_f32_16x16x32_bf16(al##ks, bh0, lh0, 0, 0, 0); \
        lh1 = __builtin_amdgcn_mfma_f32_16x16x32_bf16(al##ks, bh1, lh1, 0, 0, 0); \
        lh2 = __builtin_amdgcn_mfma_f32_16x16x32_bf16(al##ks, bh2, lh2, 0, 0, 0); \
        lh3 = __builtin_amdgcn_mfma_f32_16x16x32_bf16(al##ks, bh3, lh3, 0, 0, 0); \
        hl0 = __builtin_amdgcn_mfma_f32_16x16x32_bf16(ah##ks, bl0, hl0, 0, 0, 0); \
        hl1 = __builtin_amdgcn_mfma_f32_16x16x32_bf16(ah##ks, bl1, hl1, 0, 0, 0); \
        hl2 = __builtin_amdgcn_mfma_f32_16x16x32_bf16(ah##ks, bl2, hl2, 0, 0, 0); \
        hl3 = __builtin_amdgcn_mfma_f32_16x16x32_bf16(ah##ks, bl3, hl3, 0, 0, 0); \
    }
        REP4(KSTEP)
#undef KSTEP

        const f32x4 acc0 = hh0 + lh0 + hl0;
        const f32x4 acc1 = hh1 + lh1 + hl1;
        const f32x4 acc2 = hh2 + lh2 + hl2;
        const f32x4 acc3 = hh3 + lh3 + hl3;

        // ---- Epilogue for this column block ----
        const int colb = (cb & 1) * 64;  // col base within the 128-wide output
        if (cb < 4) {
            __bf16* __restrict__ ob = EEb + ((cb < 2) ? 0 : (size_t)N_NODES * DIM);
#define ST(s, ACC)                                                             \
            {                                                                  \
                const int col = colb + (s) * 16 + r16;                         \
                ob[(size_t)(orow + 0) * DIM + col] = (__bf16)ACC[0];           \
                ob[(size_t)(orow + 1) * DIM + col] = (__bf16)ACC[1];           \
                ob[(size_t)(orow + 2) * DIM + col] = (__bf16)ACC[2];           \
                ob[(size_t)(orow + 3) * DIM + col] = (__bf16)ACC[3];           \
            }
            ST(0, acc0) ST(1, acc1) ST(2, acc2) ST(3, acc3)
#undef ST
        } else {
#define ST(s, ACC)                                                             \
            {                                                                  \
                const int col = colb + (s) * 16 + r16;                         \
                const float bs = W_S_b[col];                                   \
                ent_S[(size_t)(orow + 0) * DIM + col] = ACC[0] + bs;           \
                ent_S[(size_t)(orow + 1) * DIM + col] = ACC[1] + bs;           \
                ent_S[(size_t)(orow + 2) * DIM + col] = ACC[2] + bs;           \
                ent_S[(size_t)(orow + 3) * DIM + col] = ACC[3] + bs;           \
            }
            ST(0, acc0) ST(1, acc1) ST(2, acc2) ST(3, acc3)
#undef ST
        }
    }
}

// ---------------------------------------------------------------------------
// CSR construction: histogram -> 3-phase exclusive scan -> fill.
// ---------------------------------------------------------------------------
__global__ void __launch_bounds__(256)
hist_kernel(const int* __restrict__ dst, int* __restrict__ counts) {
    const int e = blockIdx.x * 256 + threadIdx.x;
    if (e < N_EDGES) atomicAdd(&counts[dst[e]], 1);
}

__global__ void __launch_bounds__(SCAN_BLK)
scan1_kernel(const int* __restrict__ counts, int* __restrict__ offs,
             int* __restrict__ bsum) {
    __shared__ int tmp[SCAN_BLK];
    const int i = blockIdx.x * SCAN_BLK + threadIdx.x;
    const int v = (i < N_NODES) ? counts[i] : 0;
    tmp[threadIdx.x] = v;
    __syncthreads();
    for (int off = 1; off < SCAN_BLK; off <<= 1) {
        const int t = (threadIdx.x >= off) ? tmp[threadIdx.x - off] : 0;
        __syncthreads();
        tmp[threadIdx.x] += t;
        __syncthreads();
    }
    if (i < N_NODES) offs[i] = tmp[threadIdx.x] - v;  // exclusive
    if (threadIdx.x == SCAN_BLK - 1) bsum[blockIdx.x] = tmp[SCAN_BLK - 1];
}

__global__ void __launch_bounds__(128)
scan2_kernel(int* __restrict__ bsum) {
    __shared__ int tmp[128];
    const int i = threadIdx.x;
    const int v = (i < SCAN_NBLK) ? bsum[i] : 0;
    tmp[i] = v;
    __syncthreads();
    for (int off = 1; off < 128; off <<= 1) {
        const int tv = (i >= off) ? tmp[i - off] : 0;
        __syncthreads();
        tmp[i] += tv;
        __syncthreads();
    }
    if (i < SCAN_NBLK) bsum[i] = tmp[i] - v;  // exclusive
}

__global__ void __launch_bounds__(SCAN_BLK)
scan3_kernel(int* __restrict__ offs, const int* __restrict__ bsum) {
    const int i = blockIdx.x * SCAN_BLK + threadIdx.x;
    if (i < N_NODES) offs[i] += bsum[blockIdx.x];
}

// Fill: sorted-by-dst packed edge payload: row(17b) | etype<<17 (9b).
__global__ void __launch_bounds__(256)
fill_kernel(const int* __restrict__ src, const int* __restrict__ dst,
            const int* __restrict__ et, const int* __restrict__ offs,
            int* __restrict__ cursor, int* __restrict__ sp) {
    const int e = blockIdx.x * 256 + threadIdx.x;
    if (e >= N_EDGES) return;
    const int d = dst[e];
    const int t = et[e];
    const int row = src[e] + ((t < NUM_REL) ? 0 : N_NODES);
    const int pos = atomicAdd(&cursor[d], 1);
    sp[offs[d] + pos] = row | (t << 17);
}

// ---------------------------------------------------------------------------
// Gather-reduce: one wave per node. Lane l owns output floats [2l, 2l+1].
// EEb is bf16 (half the L3 traffic of fp32); accumulate in fp32.
// Fuses finalize: out = ent_S + acc / max(deg,1).
// ---------------------------------------------------------------------------
__global__ void __launch_bounds__(256)
gather_kernel(const int* __restrict__ offs, const int* __restrict__ counts,
              const int* __restrict__ sp, const __bf16* __restrict__ EEb,
              const float* __restrict__ R, const float* __restrict__ ent_S,
              float* __restrict__ out_ent) {
    const int node = blockIdx.x * 4 + (threadIdx.x >> 6);
    if (node >= N_NODES) return;
    const int l = threadIdx.x & 63;

    const int beg = offs[node];
    const int cnt = counts[node];

    float ax = 0.f, ay = 0.f;
    for (int base = 0; base < cnt; base += 64) {
        const int kk = min(64, cnt - base);
        const int myp = (base + l < cnt) ? sp[beg + base + l] : 0;
#pragma unroll 4
        for (int i = 0; i < kk; ++i) {
            const int p = __shfl(myp, i);
            const int row = p & 0x1FFFF;
            const int t = p >> 17;
            const unsigned int v = *(const unsigned int*)(EEb + (size_t)row * DIM + 2 * l);
            const float ex = __uint_as_float((v & 0xffffu) << 16);
            const float ey = __uint_as_float(v & 0xffff0000u);
            const float2 r = *(const float2*)(R + (size_t)t * DIM + 2 * l);
            ax += ex + r.x;
            ay += ey + r.y;
        }
    }

    const float inv = 1.0f / fmaxf((float)cnt, 1.0f);
    const float2 s = *(const float2*)(ent_S + (size_t)node * DIM + 2 * l);
    float2 o;
    o.x = s.x + ax * inv;
    o.y = s.y + ay * inv;
    *(float2*)(out_ent + (size_t)node * DIM + 2 * l) = o;
}

extern "C" void kernel_launch(void* const* d_in, const int* in_sizes, int n_in,
                              void* d_out, int out_size, void* d_ws, size_t ws_size,
                              hipStream_t stream) {
    const int* src = (const int*)d_in[0];
    const int* dst = (const int*)d_in[1];
    const int* et = (const int*)d_in[2];
    const float* ent_emb = (const float*)d_in[3];
    const float* rel_emb = (const float*)d_in[4];
    const float* W_O_w = (const float*)d_in[5];
    const float* W_O_b = (const float*)d_in[6];
    const float* W_I_w = (const float*)d_in[7];
    const float* W_I_b = (const float*)d_in[8];
    const float* W_S_w = (const float*)d_in[9];
    const float* W_S_b = (const float*)d_in[10];
    const float* W_R_w = (const float*)d_in[11];
    const float* W_R_b = (const float*)d_in[12];

    float* out_ent = (float*)d_out;                    // [50000*128]
    float* out_rel = out_ent + (size_t)N_NODES * DIM;  // [400*128]

    // Workspace layout (floats):
    // R | ent_S | EEb(bf16) | WTh | WTl | counts,cursor | bsum | offs | sp
    float* wsf = (float*)d_ws;
    float* R = wsf;
    wsf += (size_t)NREL2 * DIM;          // 51,200 f
    float* ent_S = wsf;
    wsf += (size_t)N_NODES * DIM;        // 6.4M f
    __bf16* EEb = (__bf16*)wsf;
    wsf += (size_t)N_NODES * DIM;        // 12.8M bf16 = 6.4M f
    __bf16* WTh = (__bf16*)wsf;
    wsf += 384 * DIM / 2;
    __bf16* WTl = (__bf16*)wsf;
    wsf += 384 * DIM / 2;
    int* counts = (int*)wsf;
    int* cursor = counts + N_NODES;
    int* bsum = cursor + N_NODES;
    int* offs = bsum + 128;
    int* sp = offs + N_NODES;
    // total ~56 MB

    hipMemsetAsync(counts, 0, 2 * N_NODES * sizeof(int), stream);

    rel_tables_kernel<<<NREL2, DIM, 0, stream>>>(rel_emb, W_O_w, W_O_b, W_I_w, W_I_b,
                                                 W_R_w, W_R_b, R, out_rel);

    wt_build_kernel<<<(384 * DIM + 255) / 256, 256, 0, stream>>>(
        W_O_w, W_I_w, W_S_w, WTh, WTl);

    mfma_gemm_kernel<<<(NROWG + 1) / 2, 256, 0, stream>>>(
        ent_emb, WTh, WTl, W_S_b, EEb, ent_S);

    hist_kernel<<<(N_EDGES + 255) / 256, 256, 0, stream>>>(dst, counts);
    scan1_kernel<<<SCAN_NBLK, SCAN_BLK, 0, stream>>>(counts, offs, bsum);
    scan2_kernel<<<1, 128, 0, stream>>>(bsum);
    scan3_kernel<<<SCAN_NBLK, SCAN_BLK, 0, stream>>>(offs, bsum);
    fill_kernel<<<(N_EDGES + 255) / 256, 256, 0, stream>>>(src, dst, et, offs, cursor, sp);

    gather_kernel<<<(N_NODES + 3) / 4, 256, 0, stream>>>(offs, counts, sp, EEb, R, ent_S,
                                                         out_ent);
}

// Round 9
// 214.291 us; speedup vs baseline: 1.5648x; 1.2092x over previous
//
#include <hip/hip_runtime.h>
#include <hip/hip_bf16.h>

#define N_NODES 50000
#define N_EDGES 800000
#define DIM 128
#define NUM_REL 200
#define NREL2 (2 * NUM_REL)
#define SCAN_BLK 512
#define SCAN_NBLK ((N_NODES + SCAN_BLK - 1) / SCAN_BLK)  // 98
#define NROWG (N_NODES / 16)   // 3125 row groups of 16 nodes
#define RG_PER_WAVE 5          // 3125 = 625 * 5
#define NCHUNK (NROWG / RG_PER_WAVE)  // 625
#define NWAVES (6 * NCHUNK)    // 3750

typedef __bf16 bf16x8 __attribute__((ext_vector_type(8)));
typedef float f32x4 __attribute__((ext_vector_type(4)));

// ---------------------------------------------------------------------------
// Kernel A: merged relation table R[400][128] (W_O rel-half for t<200, W_I
// rel-half else, + matching bias) and rel_new output (rel_emb @ W_R^T + b_R).
// ---------------------------------------------------------------------------
__global__ void rel_tables_kernel(const float* __restrict__ rel_emb,
                                  const float* __restrict__ W_O_w,
                                  const float* __restrict__ W_O_b,
                                  const float* __restrict__ W_I_w,
                                  const float* __restrict__ W_I_b,
                                  const float* __restrict__ W_R_w,
                                  const float* __restrict__ W_R_b,
                                  float* __restrict__ R,
                                  float* __restrict__ rel_new) {
    __shared__ float row[DIM];
    const int t = blockIdx.x;   // 0..399
    const int j = threadIdx.x;  // 0..127
    row[j] = rel_emb[t * DIM + j];
    __syncthreads();

    const bool fwd = (t < NUM_REL);
    const float* __restrict__ wSel = (fwd ? W_O_w : W_I_w) + j * (2 * DIM);
    const float* __restrict__ wR = W_R_w + j * DIM;

    float aSel = 0.f, aR = 0.f;
#pragma unroll 8
    for (int k = 0; k < DIM; ++k) {
        const float e = row[k];
        aSel += e * wSel[k];
        aR += e * wR[k];
    }
    R[t * DIM + j] = aSel + (fwd ? W_O_b[j] : W_I_b[j]);
    rel_new[t * DIM + j] = aR + W_R_b[j];
}

// ---------------------------------------------------------------------------
// Weight prep: merged WT[384][128] (row j: j<128 -> W_O ent-half row j;
// j<256 -> W_I ent-half; else W_S) split into bf16 hi/lo.
// ---------------------------------------------------------------------------
__global__ void __launch_bounds__(256)
wt_build_kernel(const float* __restrict__ W_O_w, const float* __restrict__ W_I_w,
                const float* __restrict__ W_S_w,
                __bf16* __restrict__ WTh, __bf16* __restrict__ WTl) {
    const int idx = blockIdx.x * 256 + threadIdx.x;
    if (idx >= 384 * DIM) return;
    const int j = idx >> 7;
    const int k = idx & 127;
    float v;
    if (j < 128) v = W_O_w[j * (2 * DIM) + DIM + k];
    else if (j < 256) v = W_I_w[(j - 128) * (2 * DIM) + DIM + k];
    else v = W_S_w[(j - 256) * DIM + k];
    const __bf16 h = (__bf16)v;
    WTh[idx] = h;
    WTl[idx] = (__bf16)(v - (float)h);
}

// ---------------------------------------------------------------------------
// Kernel B (v9): MFMA bf16-split GEMM, B-register-resident.
// Wave w: cb = w % 6 (64-col block), chunk = w / 6 -> 5 row-groups.
// B fragments (hi+lo, 32 x bf16x8 = 128 VGPR) loaded ONCE per wave, then the
// rg loop streams A (8 float4 / rg) and issues 48 MFMAs with ZERO global B
// traffic -> v8's per-rg B-load latency (the 6% MfmaUtil cause) is gone.
// 8 acc chains (p=hh, q=lh+hl per subtile).  __launch_bounds__(256,1) lifts
// the VGPR cap (~225 needed, 2 waves/SIMD).
// Outputs: cb 0..3 -> EEb (bf16), cb 4..5 -> ent_S (fp32, +b_S).
// ---------------------------------------------------------------------------
#define REP4(F) F(0) F(1) F(2) F(3)

__global__ void __launch_bounds__(256, 1)
mfma_gemm_kernel(const float* __restrict__ ent,
                 const __bf16* __restrict__ WTh, const __bf16* __restrict__ WTl,
                 const float* __restrict__ W_S_b,
                 __bf16* __restrict__ EEb, float* __restrict__ ent_S) {
    const int w = blockIdx.x * 4 + (threadIdx.x >> 6);
    if (w >= NWAVES) return;
    const int cb = w % 6;
    const int chunk = w / 6;
    const int rg0 = chunk * RG_PER_WAVE;
    const int l = threadIdx.x & 63;
    const int r16 = l & 15;  // row (A) / col (B,D)
    const int kg = l >> 4;   // k-subgroup 0..3

    const int c0 = cb * 64;
    const __bf16* __restrict__ bb = WTh + (size_t)(c0 + r16) * DIM + kg * 8;
    const ptrdiff_t dlo = WTl - WTh;

    // ---- Load B fragments once: Bh_s_ks / Bl_s_ks (32 x bf16x8) ----
#define BDECL(s, ks)                                                           \
    const bf16x8 Bh_##s##_##ks =                                               \
        *(const bf16x8*)(bb + (size_t)(s) * 16 * DIM + (ks) * 32);             \
    const bf16x8 Bl_##s##_##ks =                                               \
        *(const bf16x8*)(bb + dlo + (size_t)(s) * 16 * DIM + (ks) * 32);
#define BROW(s) BDECL(s, 0) BDECL(s, 1) BDECL(s, 2) BDECL(s, 3)
    REP4(BROW)
#undef BROW
#undef BDECL

    // Output base for this cb (wave-uniform).
    const int colb = (cb & 1) * 64;
    __bf16* __restrict__ obb =
        (cb < 4) ? (EEb + ((cb < 2) ? 0 : (size_t)N_NODES * DIM)) : (__bf16*)0;

#pragma unroll 1
    for (int rg = rg0; rg < rg0 + RG_PER_WAVE; ++rg) {
        // ---- Load & convert A fragments for this row-group ----
        const float* __restrict__ aptr = ent + (size_t)(rg * 16 + r16) * DIM + kg * 8;
#define ADECL(ks)                                                              \
        bf16x8 ah##ks, al##ks;                                                 \
        {                                                                      \
            const float4 v0 = *(const float4*)(aptr + (ks) * 32);              \
            const float4 v1 = *(const float4*)(aptr + (ks) * 32 + 4);          \
            const float xs[8] = {v0.x, v0.y, v0.z, v0.w, v1.x, v1.y, v1.z, v1.w}; \
            _Pragma("unroll") for (int i = 0; i < 8; ++i) {                    \
                const __bf16 h = (__bf16)xs[i];                                \
                ah##ks[i] = h;                                                 \
                al##ks[i] = (__bf16)(xs[i] - (float)h);                        \
            }                                                                  \
        }
        REP4(ADECL)
#undef ADECL

        f32x4 p0 = {0.f, 0.f, 0.f, 0.f}, q0 = {0.f, 0.f, 0.f, 0.f};
        f32x4 p1 = {0.f, 0.f, 0.f, 0.f}, q1 = {0.f, 0.f, 0.f, 0.f};
        f32x4 p2 = {0.f, 0.f, 0.f, 0.f}, q2 = {0.f, 0.f, 0.f, 0.f};
        f32x4 p3 = {0.f, 0.f, 0.f, 0.f}, q3 = {0.f, 0.f, 0.f, 0.f};

#define KS(ks)                                                                 \
        p0 = __builtin_amdgcn_mfma_f32_16x16x32_bf16(ah##ks, Bh_0_##ks, p0, 0, 0, 0); \
        p1 = __builtin_amdgcn_mfma_f32_16x16x32_bf16(ah##ks, Bh_1_##ks, p1, 0, 0, 0); \
        p2 = __builtin_amdgcn_mfma_f32_16x16x32_bf16(ah##ks, Bh_2_##ks, p2, 0, 0, 0); \
        p3 = __builtin_amdgcn_mfma_f32_16x16x32_bf16(ah##ks, Bh_3_##ks, p3, 0, 0, 0); \
        q0 = __builtin_amdgcn_mfma_f32_16x16x32_bf16(al##ks, Bh_0_##ks, q0, 0, 0, 0); \
        q1 = __builtin_amdgcn_mfma_f32_16x16x32_bf16(al##ks, Bh_1_##ks, q1, 0, 0, 0); \
        q2 = __builtin_amdgcn_mfma_f32_16x16x32_bf16(al##ks, Bh_2_##ks, q2, 0, 0, 0); \
        q3 = __builtin_amdgcn_mfma_f32_16x16x32_bf16(al##ks, Bh_3_##ks, q3, 0, 0, 0); \
        q0 = __builtin_amdgcn_mfma_f32_16x16x32_bf16(ah##ks, Bl_0_##ks, q0, 0, 0, 0); \
        q1 = __builtin_amdgcn_mfma_f32_16x16x32_bf16(ah##ks, Bl_1_##ks, q1, 0, 0, 0); \
        q2 = __builtin_amdgcn_mfma_f32_16x16x32_bf16(ah##ks, Bl_2_##ks, q2, 0, 0, 0); \
        q3 = __builtin_amdgcn_mfma_f32_16x16x32_bf16(ah##ks, Bl_3_##ks, q3, 0, 0, 0);
        REP4(KS)
#undef KS

        const int orow = rg * 16 + kg * 4;
        if (cb < 4) {
#define ST(s, P, Q)                                                            \
            {                                                                  \
                const int col = colb + (s) * 16 + r16;                         \
                const f32x4 a = P + Q;                                         \
                obb[(size_t)(orow + 0) * DIM + col] = (__bf16)a[0];            \
                obb[(size_t)(orow + 1) * DIM + col] = (__bf16)a[1];            \
                obb[(size_t)(orow + 2) * DIM + col] = (__bf16)a[2];            \
                obb[(size_t)(orow + 3) * DIM + col] = (__bf16)a[3];            \
            }
            ST(0, p0, q0) ST(1, p1, q1) ST(2, p2, q2) ST(3, p3, q3)
#undef ST
        } else {
#define ST(s, P, Q)                                                            \
            {                                                                  \
                const int col = colb + (s) * 16 + r16;                         \
                const float bs = W_S_b[col];                                   \
                const f32x4 a = P + Q;                                         \
                ent_S[(size_t)(orow + 0) * DIM + col] = a[0] + bs;             \
                ent_S[(size_t)(orow + 1) * DIM + col] = a[1] + bs;             \
                ent_S[(size_t)(orow + 2) * DIM + col] = a[2] + bs;             \
                ent_S[(size_t)(orow + 3) * DIM + col] = a[3] + bs;             \
            }
            ST(0, p0, q0) ST(1, p1, q1) ST(2, p2, q2) ST(3, p3, q3)
#undef ST
        }
    }
}

// ---------------------------------------------------------------------------
// CSR construction: histogram -> 3-phase exclusive scan -> fill.
// ---------------------------------------------------------------------------
__global__ void __launch_bounds__(256)
hist_kernel(const int* __restrict__ dst, int* __restrict__ counts) {
    const int e = blockIdx.x * 256 + threadIdx.x;
    if (e < N_EDGES) atomicAdd(&counts[dst[e]], 1);
}

__global__ void __launch_bounds__(SCAN_BLK)
scan1_kernel(const int* __restrict__ counts, int* __restrict__ offs,
             int* __restrict__ bsum) {
    __shared__ int tmp[SCAN_BLK];
    const int i = blockIdx.x * SCAN_BLK + threadIdx.x;
    const int v = (i < N_NODES) ? counts[i] : 0;
    tmp[threadIdx.x] = v;
    __syncthreads();
    for (int off = 1; off < SCAN_BLK; off <<= 1) {
        const int t = (threadIdx.x >= off) ? tmp[threadIdx.x - off] : 0;
        __syncthreads();
        tmp[threadIdx.x] += t;
        __syncthreads();
    }
    if (i < N_NODES) offs[i] = tmp[threadIdx.x] - v;  // exclusive
    if (threadIdx.x == SCAN_BLK - 1) bsum[blockIdx.x] = tmp[SCAN_BLK - 1];
}

__global__ void __launch_bounds__(128)
scan2_kernel(int* __restrict__ bsum) {
    __shared__ int tmp[128];
    const int i = threadIdx.x;
    const int v = (i < SCAN_NBLK) ? bsum[i] : 0;
    tmp[i] = v;
    __syncthreads();
    for (int off = 1; off < 128; off <<= 1) {
        const int tv = (i >= off) ? tmp[i - off] : 0;
        __syncthreads();
        tmp[i] += tv;
        __syncthreads();
    }
    if (i < SCAN_NBLK) bsum[i] = tmp[i] - v;  // exclusive
}

__global__ void __launch_bounds__(SCAN_BLK)
scan3_kernel(int* __restrict__ offs, const int* __restrict__ bsum) {
    const int i = blockIdx.x * SCAN_BLK + threadIdx.x;
    if (i < N_NODES) offs[i] += bsum[blockIdx.x];
}

// Fill: sorted-by-dst packed edge payload: row(17b) | etype<<17 (9b).
__global__ void __launch_bounds__(256)
fill_kernel(const int* __restrict__ src, const int* __restrict__ dst,
            const int* __restrict__ et, const int* __restrict__ offs,
            int* __restrict__ cursor, int* __restrict__ sp) {
    const int e = blockIdx.x * 256 + threadIdx.x;
    if (e >= N_EDGES) return;
    const int d = dst[e];
    const int t = et[e];
    const int row = src[e] + ((t < NUM_REL) ? 0 : N_NODES);
    const int pos = atomicAdd(&cursor[d], 1);
    sp[offs[d] + pos] = row | (t << 17);
}

// ---------------------------------------------------------------------------
// Gather-reduce: one wave per node. Lane l owns output floats [2l, 2l+1].
// EEb is bf16 (half the L3 traffic of fp32); accumulate in fp32.
// Fuses finalize: out = ent_S + acc / max(deg,1).
// ---------------------------------------------------------------------------
__global__ void __launch_bounds__(256)
gather_kernel(const int* __restrict__ offs, const int* __restrict__ counts,
              const int* __restrict__ sp, const __bf16* __restrict__ EEb,
              const float* __restrict__ R, const float* __restrict__ ent_S,
              float* __restrict__ out_ent) {
    const int node = blockIdx.x * 4 + (threadIdx.x >> 6);
    if (node >= N_NODES) return;
    const int l = threadIdx.x & 63;

    const int beg = offs[node];
    const int cnt = counts[node];

    float ax = 0.f, ay = 0.f;
    for (int base = 0; base < cnt; base += 64) {
        const int kk = min(64, cnt - base);
        const int myp = (base + l < cnt) ? sp[beg + base + l] : 0;
#pragma unroll 4
        for (int i = 0; i < kk; ++i) {
            const int p = __shfl(myp, i);
            const int row = p & 0x1FFFF;
            const int t = p >> 17;
            const unsigned int v = *(const unsigned int*)(EEb + (size_t)row * DIM + 2 * l);
            const float ex = __uint_as_float((v & 0xffffu) << 16);
            const float ey = __uint_as_float(v & 0xffff0000u);
            const float2 r = *(const float2*)(R + (size_t)t * DIM + 2 * l);
            ax += ex + r.x;
            ay += ey + r.y;
        }
    }

    const float inv = 1.0f / fmaxf((float)cnt, 1.0f);
    const float2 s = *(const float2*)(ent_S + (size_t)node * DIM + 2 * l);
    float2 o;
    o.x = s.x + ax * inv;
    o.y = s.y + ay * inv;
    *(float2*)(out_ent + (size_t)node * DIM + 2 * l) = o;
}

extern "C" void kernel_launch(void* const* d_in, const int* in_sizes, int n_in,
                              void* d_out, int out_size, void* d_ws, size_t ws_size,
                              hipStream_t stream) {
    const int* src = (const int*)d_in[0];
    const int* dst = (const int*)d_in[1];
    const int* et = (const int*)d_in[2];
    const float* ent_emb = (const float*)d_in[3];
    const float* rel_emb = (const float*)d_in[4];
    const float* W_O_w = (const float*)d_in[5];
    const float* W_O_b = (const float*)d_in[6];
    const float* W_I_w = (const float*)d_in[7];
    const float* W_I_b = (const float*)d_in[8];
    const float* W_S_w = (const float*)d_in[9];
    const float* W_S_b = (const float*)d_in[10];
    const float* W_R_w = (const float*)d_in[11];
    const float* W_R_b = (const float*)d_in[12];

    float* out_ent = (float*)d_out;                    // [50000*128]
    float* out_rel = out_ent + (size_t)N_NODES * DIM;  // [400*128]

    // Workspace layout (floats):
    // R | ent_S | EEb(bf16) | WTh | WTl | counts,cursor | bsum | offs | sp
    float* wsf = (float*)d_ws;
    float* R = wsf;
    wsf += (size_t)NREL2 * DIM;          // 51,200 f
    float* ent_S = wsf;
    wsf += (size_t)N_NODES * DIM;        // 6.4M f
    __bf16* EEb = (__bf16*)wsf;
    wsf += (size_t)N_NODES * DIM;        // 12.8M bf16 = 6.4M f
    __bf16* WTh = (__bf16*)wsf;
    wsf += 384 * DIM / 2;
    __bf16* WTl = (__bf16*)wsf;
    wsf += 384 * DIM / 2;
    int* counts = (int*)wsf;
    int* cursor = counts + N_NODES;
    int* bsum = cursor + N_NODES;
    int* offs = bsum + 128;
    int* sp = offs + N_NODES;
    // total ~56 MB

    hipMemsetAsync(counts, 0, 2 * N_NODES * sizeof(int), stream);

    rel_tables_kernel<<<NREL2, DIM, 0, stream>>>(rel_emb, W_O_w, W_O_b, W_I_w, W_I_b,
                                                 W_R_w, W_R_b, R, out_rel);

    wt_build_kernel<<<(384 * DIM + 255) / 256, 256, 0, stream>>>(
        W_O_w, W_I_w, W_S_w, WTh, WTl);

    mfma_gemm_kernel<<<(NWAVES + 3) / 4, 256, 0, stream>>>(
        ent_emb, WTh, WTl, W_S_b, EEb, ent_S);

    hist_kernel<<<(N_EDGES + 255) / 256, 256, 0, stream>>>(dst, counts);
    scan1_kernel<<<SCAN_NBLK, SCAN_BLK, 0, stream>>>(counts, offs, bsum);
    scan2_kernel<<<1, 128, 0, stream>>>(bsum);
    scan3_kernel<<<SCAN_NBLK, SCAN_BLK, 0, stream>>>(offs, bsum);
    fill_kernel<<<(N_EDGES + 255) / 256, 256, 0, stream>>>(src, dst, et, offs, cursor, sp);

    gather_kernel<<<(N_NODES + 3) / 4, 256, 0, stream>>>(offs, counts, sp, EEb, R, ent_S,
                                                         out_ent);
}

// Round 10
// 201.705 us; speedup vs baseline: 1.6624x; 1.0624x over previous
//
#include <hip/hip_runtime.h>
#include <hip/hip_bf16.h>

#define N_NODES 50000
#define N_EDGES 800000
#define DIM 128
#define NUM_REL 200
#define NREL2 (2 * NUM_REL)
#define SCAN_BLK 512
#define SCAN_NBLK ((N_NODES + SCAN_BLK - 1) / SCAN_BLK)  // 98
#define NROWG (N_NODES / 16)   // 3125 row groups of 16 nodes
#define RG_PER_WAVE 5          // 3125 = 625 * 5
#define NCHUNK (NROWG / RG_PER_WAVE)  // 625
#define NWAVES (6 * NCHUNK)    // 3750
// Zero-row padding: EEb row 100000 and Rb row 400 are all-zero.
#define ZROW (2 * N_NODES)
#define ZREL NREL2
#define ZPAY (ZROW | (ZREL << 17))

typedef __bf16 bf16x8 __attribute__((ext_vector_type(8)));
typedef float f32x4 __attribute__((ext_vector_type(4)));

// ---------------------------------------------------------------------------
// Kernel A: merged relation table Rb[401][128] in bf16 (W_O rel-half +b for
// t<200, W_I rel-half +b else; row 400 zeroed by memset) and rel_new output
// (rel_emb @ W_R^T + b_R, fp32).
// ---------------------------------------------------------------------------
__global__ void rel_tables_kernel(const float* __restrict__ rel_emb,
                                  const float* __restrict__ W_O_w,
                                  const float* __restrict__ W_O_b,
                                  const float* __restrict__ W_I_w,
                                  const float* __restrict__ W_I_b,
                                  const float* __restrict__ W_R_w,
                                  const float* __restrict__ W_R_b,
                                  __bf16* __restrict__ Rb,
                                  float* __restrict__ rel_new) {
    __shared__ float row[DIM];
    const int t = blockIdx.x;   // 0..399
    const int j = threadIdx.x;  // 0..127
    row[j] = rel_emb[t * DIM + j];
    __syncthreads();

    const bool fwd = (t < NUM_REL);
    const float* __restrict__ wSel = (fwd ? W_O_w : W_I_w) + j * (2 * DIM);
    const float* __restrict__ wR = W_R_w + j * DIM;

    float aSel = 0.f, aR = 0.f;
#pragma unroll 8
    for (int k = 0; k < DIM; ++k) {
        const float e = row[k];
        aSel += e * wSel[k];
        aR += e * wR[k];
    }
    Rb[t * DIM + j] = (__bf16)(aSel + (fwd ? W_O_b[j] : W_I_b[j]));
    rel_new[t * DIM + j] = aR + W_R_b[j];
}

// ---------------------------------------------------------------------------
// Weight prep: merged WT[384][128] (row j: j<128 -> W_O ent-half row j;
// j<256 -> W_I ent-half; else W_S) split into bf16 hi/lo.
// ---------------------------------------------------------------------------
__global__ void __launch_bounds__(256)
wt_build_kernel(const float* __restrict__ W_O_w, const float* __restrict__ W_I_w,
                const float* __restrict__ W_S_w,
                __bf16* __restrict__ WTh, __bf16* __restrict__ WTl) {
    const int idx = blockIdx.x * 256 + threadIdx.x;
    if (idx >= 384 * DIM) return;
    const int j = idx >> 7;
    const int k = idx & 127;
    float v;
    if (j < 128) v = W_O_w[j * (2 * DIM) + DIM + k];
    else if (j < 256) v = W_I_w[(j - 128) * (2 * DIM) + DIM + k];
    else v = W_S_w[(j - 256) * DIM + k];
    const __bf16 h = (__bf16)v;
    WTh[idx] = h;
    WTl[idx] = (__bf16)(v - (float)h);
}

// ---------------------------------------------------------------------------
// Kernel B (v9, unchanged): MFMA bf16-split GEMM, B-register-resident.
// ---------------------------------------------------------------------------
#define REP4(F) F(0) F(1) F(2) F(3)

__global__ void __launch_bounds__(256, 1)
mfma_gemm_kernel(const float* __restrict__ ent,
                 const __bf16* __restrict__ WTh, const __bf16* __restrict__ WTl,
                 const float* __restrict__ W_S_b,
                 __bf16* __restrict__ EEb, float* __restrict__ ent_S) {
    const int w = blockIdx.x * 4 + (threadIdx.x >> 6);
    if (w >= NWAVES) return;
    const int cb = w % 6;
    const int chunk = w / 6;
    const int rg0 = chunk * RG_PER_WAVE;
    const int l = threadIdx.x & 63;
    const int r16 = l & 15;  // row (A) / col (B,D)
    const int kg = l >> 4;   // k-subgroup 0..3

    const int c0 = cb * 64;
    const __bf16* __restrict__ bb = WTh + (size_t)(c0 + r16) * DIM + kg * 8;
    const ptrdiff_t dlo = WTl - WTh;

#define BDECL(s, ks)                                                           \
    const bf16x8 Bh_##s##_##ks =                                               \
        *(const bf16x8*)(bb + (size_t)(s) * 16 * DIM + (ks) * 32);             \
    const bf16x8 Bl_##s##_##ks =                                               \
        *(const bf16x8*)(bb + dlo + (size_t)(s) * 16 * DIM + (ks) * 32);
#define BROW(s) BDECL(s, 0) BDECL(s, 1) BDECL(s, 2) BDECL(s, 3)
    REP4(BROW)
#undef BROW
#undef BDECL

    const int colb = (cb & 1) * 64;
    __bf16* __restrict__ obb =
        (cb < 4) ? (EEb + ((cb < 2) ? 0 : (size_t)N_NODES * DIM)) : (__bf16*)0;

#pragma unroll 1
    for (int rg = rg0; rg < rg0 + RG_PER_WAVE; ++rg) {
        const float* __restrict__ aptr = ent + (size_t)(rg * 16 + r16) * DIM + kg * 8;
#define ADECL(ks)                                                              \
        bf16x8 ah##ks, al##ks;                                                 \
        {                                                                      \
            const float4 v0 = *(const float4*)(aptr + (ks) * 32);              \
            const float4 v1 = *(const float4*)(aptr + (ks) * 32 + 4);          \
            const float xs[8] = {v0.x, v0.y, v0.z, v0.w, v1.x, v1.y, v1.z, v1.w}; \
            _Pragma("unroll") for (int i = 0; i < 8; ++i) {                    \
                const __bf16 h = (__bf16)xs[i];                                \
                ah##ks[i] = h;                                                 \
                al##ks[i] = (__bf16)(xs[i] - (float)h);                        \
            }                                                                  \
        }
        REP4(ADECL)
#undef ADECL

        f32x4 p0 = {0.f, 0.f, 0.f, 0.f}, q0 = {0.f, 0.f, 0.f, 0.f};
        f32x4 p1 = {0.f, 0.f, 0.f, 0.f}, q1 = {0.f, 0.f, 0.f, 0.f};
        f32x4 p2 = {0.f, 0.f, 0.f, 0.f}, q2 = {0.f, 0.f, 0.f, 0.f};
        f32x4 p3 = {0.f, 0.f, 0.f, 0.f}, q3 = {0.f, 0.f, 0.f, 0.f};

#define KS(ks)                                                                 \
        p0 = __builtin_amdgcn_mfma_f32_16x16x32_bf16(ah##ks, Bh_0_##ks, p0, 0, 0, 0); \
        p1 = __builtin_amdgcn_mfma_f32_16x16x32_bf16(ah##ks, Bh_1_##ks, p1, 0, 0, 0); \
        p2 = __builtin_amdgcn_mfma_f32_16x16x32_bf16(ah##ks, Bh_2_##ks, p2, 0, 0, 0); \
        p3 = __builtin_amdgcn_mfma_f32_16x16x32_bf16(ah##ks, Bh_3_##ks, p3, 0, 0, 0); \
        q0 = __builtin_amdgcn_mfma_f32_16x16x32_bf16(al##ks, Bh_0_##ks, q0, 0, 0, 0); \
        q1 = __builtin_amdgcn_mfma_f32_16x16x32_bf16(al##ks, Bh_1_##ks, q1, 0, 0, 0); \
        q2 = __builtin_amdgcn_mfma_f32_16x16x32_bf16(al##ks, Bh_2_##ks, q2, 0, 0, 0); \
        q3 = __builtin_amdgcn_mfma_f32_16x16x32_bf16(al##ks, Bh_3_##ks, q3, 0, 0, 0); \
        q0 = __builtin_amdgcn_mfma_f32_16x16x32_bf16(ah##ks, Bl_0_##ks, q0, 0, 0, 0); \
        q1 = __builtin_amdgcn_mfma_f32_16x16x32_bf16(ah##ks, Bl_1_##ks, q1, 0, 0, 0); \
        q2 = __builtin_amdgcn_mfma_f32_16x16x32_bf16(ah##ks, Bl_2_##ks, q2, 0, 0, 0); \
        q3 = __builtin_amdgcn_mfma_f32_16x16x32_bf16(ah##ks, Bl_3_##ks, q3, 0, 0, 0);
        REP4(KS)
#undef KS

        const int orow = rg * 16 + kg * 4;
        if (cb < 4) {
#define ST(s, P, Q)                                                            \
            {                                                                  \
                const int col = colb + (s) * 16 + r16;                         \
                const f32x4 a = P + Q;                                         \
                obb[(size_t)(orow + 0) * DIM + col] = (__bf16)a[0];            \
                obb[(size_t)(orow + 1) * DIM + col] = (__bf16)a[1];            \
                obb[(size_t)(orow + 2) * DIM + col] = (__bf16)a[2];            \
                obb[(size_t)(orow + 3) * DIM + col] = (__bf16)a[3];            \
            }
            ST(0, p0, q0) ST(1, p1, q1) ST(2, p2, q2) ST(3, p3, q3)
#undef ST
        } else {
#define ST(s, P, Q)                                                            \
            {                                                                  \
                const int col = colb + (s) * 16 + r16;                         \
                const float bs = W_S_b[col];                                   \
                const f32x4 a = P + Q;                                         \
                ent_S[(size_t)(orow + 0) * DIM + col] = a[0] + bs;             \
                ent_S[(size_t)(orow + 1) * DIM + col] = a[1] + bs;             \
                ent_S[(size_t)(orow + 2) * DIM + col] = a[2] + bs;             \
                ent_S[(size_t)(orow + 3) * DIM + col] = a[3] + bs;             \
            }
            ST(0, p0, q0) ST(1, p1, q1) ST(2, p2, q2) ST(3, p3, q3)
#undef ST
        }
    }
}

// ---------------------------------------------------------------------------
// CSR construction: histogram -> 3-phase exclusive scan -> fill.
// ---------------------------------------------------------------------------
__global__ void __launch_bounds__(256)
hist_kernel(const int* __restrict__ dst, int* __restrict__ counts) {
    const int e = blockIdx.x * 256 + threadIdx.x;
    if (e < N_EDGES) atomicAdd(&counts[dst[e]], 1);
}

__global__ void __launch_bounds__(SCAN_BLK)
scan1_kernel(const int* __restrict__ counts, int* __restrict__ offs,
             int* __restrict__ bsum) {
    __shared__ int tmp[SCAN_BLK];
    const int i = blockIdx.x * SCAN_BLK + threadIdx.x;
    const int v = (i < N_NODES) ? counts[i] : 0;
    tmp[threadIdx.x] = v;
    __syncthreads();
    for (int off = 1; off < SCAN_BLK; off <<= 1) {
        const int t = (threadIdx.x >= off) ? tmp[threadIdx.x - off] : 0;
        __syncthreads();
        tmp[threadIdx.x] += t;
        __syncthreads();
    }
    if (i < N_NODES) offs[i] = tmp[threadIdx.x] - v;  // exclusive
    if (threadIdx.x == SCAN_BLK - 1) bsum[blockIdx.x] = tmp[SCAN_BLK - 1];
}

__global__ void __launch_bounds__(128)
scan2_kernel(int* __restrict__ bsum) {
    __shared__ int tmp[128];
    const int i = threadIdx.x;
    const int v = (i < SCAN_NBLK) ? bsum[i] : 0;
    tmp[i] = v;
    __syncthreads();
    for (int off = 1; off < 128; off <<= 1) {
        const int tv = (i >= off) ? tmp[i - off] : 0;
        __syncthreads();
        tmp[i] += tv;
        __syncthreads();
    }
    if (i < SCAN_NBLK) bsum[i] = tmp[i] - v;  // exclusive
}

__global__ void __launch_bounds__(SCAN_BLK)
scan3_kernel(int* __restrict__ offs, const int* __restrict__ bsum) {
    const int i = blockIdx.x * SCAN_BLK + threadIdx.x;
    if (i < N_NODES) offs[i] += bsum[blockIdx.x];
}

// Fill: sorted-by-dst packed edge payload: row(17b) | etype<<17 (9b).
__global__ void __launch_bounds__(256)
fill_kernel(const int* __restrict__ src, const int* __restrict__ dst,
            const int* __restrict__ et, const int* __restrict__ offs,
            int* __restrict__ cursor, int* __restrict__ sp) {
    const int e = blockIdx.x * 256 + threadIdx.x;
    if (e >= N_EDGES) return;
    const int d = dst[e];
    const int t = et[e];
    const int row = src[e] + ((t < NUM_REL) ? 0 : N_NODES);
    const int pos = atomicAdd(&cursor[d], 1);
    sp[offs[d] + pos] = row | (t << 17);
}

// ---------------------------------------------------------------------------
// Gather-reduce v2: one wave per node, TWO edges per iteration.
// Half-wave h = l>>5 handles edge 2i+h; lane m = l&31 covers 8 B (4 bf16 cols)
// of the 256 B row.  Invalid slots load the all-zero pad rows (EEb row
// 100000 / Rb row 400) -> branch-free inner loop.  Rb in bf16 halves the
// biggest L2 stream (was 410 MB fp32).  Cross-half shfl_xor(32) reduce,
// then fused finalize: out = ent_S + acc / max(deg,1), float4 store.
// ---------------------------------------------------------------------------
__global__ void __launch_bounds__(256)
gather_kernel(const int* __restrict__ offs, const int* __restrict__ counts,
              const int* __restrict__ sp, const __bf16* __restrict__ EEb,
              const __bf16* __restrict__ Rb, const float* __restrict__ ent_S,
              float* __restrict__ out_ent) {
    const int node = blockIdx.x * 4 + (threadIdx.x >> 6);
    if (node >= N_NODES) return;
    const int l = threadIdx.x & 63;
    const int h = l >> 5;
    const int m = l & 31;

    const int beg = offs[node];
    const int cnt = counts[node];

    float a0 = 0.f, a1 = 0.f, a2 = 0.f, a3 = 0.f;
    const char* __restrict__ Eb = (const char*)EEb + 8 * m;
    const char* __restrict__ Rp = (const char*)Rb + 8 * m;

    for (int base = 0; base < cnt; base += 64) {
        const int kk = min(64, cnt - base);
        const int myp = (base + l < cnt) ? sp[beg + base + l] : ZPAY;
        for (int i = 0; i < kk; i += 2) {
            const int p = __shfl(myp, i + h);
            const unsigned eoff = (unsigned)(p & 0x1FFFF) << 8;
            const unsigned roff = ((unsigned)p >> 17) << 8;
            const uint2 ev = *(const uint2*)(Eb + eoff);
            const uint2 rv = *(const uint2*)(Rp + roff);
            a0 += __uint_as_float(ev.x << 16) + __uint_as_float(rv.x << 16);
            a1 += __uint_as_float(ev.x & 0xffff0000u) +
                  __uint_as_float(rv.x & 0xffff0000u);
            a2 += __uint_as_float(ev.y << 16) + __uint_as_float(rv.y << 16);
            a3 += __uint_as_float(ev.y & 0xffff0000u) +
                  __uint_as_float(rv.y & 0xffff0000u);
        }
    }

    a0 += __shfl_xor(a0, 32);
    a1 += __shfl_xor(a1, 32);
    a2 += __shfl_xor(a2, 32);
    a3 += __shfl_xor(a3, 32);

    if (h == 0) {
        const float inv = 1.0f / fmaxf((float)cnt, 1.0f);
        const float4 s = *(const float4*)(ent_S + (size_t)node * DIM + 4 * m);
        float4 o;
        o.x = s.x + a0 * inv;
        o.y = s.y + a1 * inv;
        o.z = s.z + a2 * inv;
        o.w = s.w + a3 * inv;
        *(float4*)(out_ent + (size_t)node * DIM + 4 * m) = o;
    }
}

extern "C" void kernel_launch(void* const* d_in, const int* in_sizes, int n_in,
                              void* d_out, int out_size, void* d_ws, size_t ws_size,
                              hipStream_t stream) {
    const int* src = (const int*)d_in[0];
    const int* dst = (const int*)d_in[1];
    const int* et = (const int*)d_in[2];
    const float* ent_emb = (const float*)d_in[3];
    const float* rel_emb = (const float*)d_in[4];
    const float* W_O_w = (const float*)d_in[5];
    const float* W_O_b = (const float*)d_in[6];
    const float* W_I_w = (const float*)d_in[7];
    const float* W_I_b = (const float*)d_in[8];
    const float* W_S_w = (const float*)d_in[9];
    const float* W_S_b = (const float*)d_in[10];
    const float* W_R_w = (const float*)d_in[11];
    const float* W_R_b = (const float*)d_in[12];

    float* out_ent = (float*)d_out;                    // [50000*128]
    float* out_rel = out_ent + (size_t)N_NODES * DIM;  // [400*128]

    // Workspace layout (floats):
    // ent_S | EEb(bf16, 100001 rows) | Rb(bf16, 401 rows) | WTh | WTl | ints
    float* wsf = (float*)d_ws;
    float* ent_S = wsf;
    wsf += (size_t)N_NODES * DIM;            // 6.4M f
    __bf16* EEb = (__bf16*)wsf;
    wsf += ((size_t)(2 * N_NODES + 1) * DIM + 1) / 2;  // 100001 rows bf16
    __bf16* Rb = (__bf16*)wsf;
    wsf += (size_t)(NREL2 + 1) * DIM / 2;    // 401 rows bf16
    __bf16* WTh = (__bf16*)wsf;
    wsf += 384 * DIM / 2;
    __bf16* WTl = (__bf16*)wsf;
    wsf += 384 * DIM / 2;
    int* counts = (int*)wsf;
    int* cursor = counts + N_NODES;
    int* bsum = cursor + N_NODES;
    int* offs = bsum + 128;
    int* sp = offs + N_NODES;
    // total ~56 MB

    hipMemsetAsync(counts, 0, 2 * N_NODES * sizeof(int), stream);
    // Zero pad rows (EEb row 100000, Rb row 400).
    hipMemsetAsync(EEb + (size_t)ZROW * DIM, 0, DIM * sizeof(__bf16), stream);
    hipMemsetAsync(Rb + (size_t)ZREL * DIM, 0, DIM * sizeof(__bf16), stream);

    rel_tables_kernel<<<NREL2, DIM, 0, stream>>>(rel_emb, W_O_w, W_O_b, W_I_w, W_I_b,
                                                 W_R_w, W_R_b, Rb, out_rel);

    wt_build_kernel<<<(384 * DIM + 255) / 256, 256, 0, stream>>>(
        W_O_w, W_I_w, W_S_w, WTh, WTl);

    mfma_gemm_kernel<<<(NWAVES + 3) / 4, 256, 0, stream>>>(
        ent_emb, WTh, WTl, W_S_b, EEb, ent_S);

    hist_kernel<<<(N_EDGES + 255) / 256, 256, 0, stream>>>(dst, counts);
    scan1_kernel<<<SCAN_NBLK, SCAN_BLK, 0, stream>>>(counts, offs, bsum);
    scan2_kernel<<<1, 128, 0, stream>>>(bsum);
    scan3_kernel<<<SCAN_NBLK, SCAN_BLK, 0, stream>>>(offs, bsum);
    fill_kernel<<<(N_EDGES + 255) / 256, 256, 0, stream>>>(src, dst, et, offs, cursor, sp);

    gather_kernel<<<(N_NODES + 3) / 4, 256, 0, stream>>>(offs, counts, sp, EEb, Rb,
                                                         ent_S, out_ent);
}